// Round 1
// baseline (1674.206 us; speedup 1.0000x reference)
//
#include <hip/hip_runtime.h>
#include <stdint.h>

#define N_NODES 50000
#define N_EDGES 1600000
#define HID 64
#define NREL 3

// ---------------------------------------------------------------------------
// CSR build: edge types, per-(node,rel) counts, offsets (scan), scatter
// ---------------------------------------------------------------------------
__global__ __launch_bounds__(256) void k_prep(const int* __restrict__ ei,
                                              const float* __restrict__ ea,
                                              int* __restrict__ src32,
                                              int* __restrict__ dstrel,
                                              int* __restrict__ cnt3) {
  int e = blockIdx.x * 256 + threadIdx.x;   // grid exact: 6250*256 = 1.6M
  float dist = ea[e * 6];
  int rel = (dist > 5000.0f) + (dist > 10000.0f);
  int s = ei[e];
  int d = ei[N_EDGES + e];
  src32[e] = s;
  dstrel[e] = d | (rel << 20);   // d < 2^17, rel in bits 20..21
  atomicAdd(&cnt3[d * 3 + rel], 1);
}

// single-block scan of node degrees -> exclusive offsets
__global__ __launch_bounds__(1024) void k_scan(const int* __restrict__ cnt3,
                                               int* __restrict__ offsets) {
  __shared__ int sums[1024];
  const int CH = 49;  // ceil(50000/1024)
  int t = threadIdx.x;
  int start = t * CH;
  int local = 0;
  for (int i = 0; i < CH; i++) {
    int n = start + i;
    if (n < N_NODES) local += cnt3[3 * n] + cnt3[3 * n + 1] + cnt3[3 * n + 2];
  }
  sums[t] = local;
  __syncthreads();
  // Hillis-Steele inclusive scan over 1024
  for (int ofs = 1; ofs < 1024; ofs <<= 1) {
    int v = (t >= ofs) ? sums[t - ofs] : 0;
    __syncthreads();
    sums[t] += v;
    __syncthreads();
  }
  int base = (t == 0) ? 0 : sums[t - 1];
  for (int i = 0; i < CH; i++) {
    int n = start + i;
    if (n < N_NODES) {
      offsets[n] = base;
      base += cnt3[3 * n] + cnt3[3 * n + 1] + cnt3[3 * n + 2];
    }
  }
}

__global__ __launch_bounds__(256) void k_scatter(const int* __restrict__ src32,
                                                 const int* __restrict__ dstrel,
                                                 const int* __restrict__ offsets,
                                                 int* __restrict__ cursor,
                                                 uint32_t* __restrict__ csr) {
  int e = blockIdx.x * 256 + threadIdx.x;
  int dr = dstrel[e];
  int d = dr & 0xFFFFF;
  int r = dr >> 20;
  int p = offsets[d] + atomicAdd(&cursor[d], 1);
  csr[p] = (uint32_t)src32[e] | ((uint32_t)r << 16);   // src < 65536
}

// ---------------------------------------------------------------------------
// Layer 0: din=3. One thread per node.
// ---------------------------------------------------------------------------
__global__ __launch_bounds__(256) void k_layer0(const float* __restrict__ x,
                                                const float* __restrict__ W0,    // [3][3][64]
                                                const float* __restrict__ root0, // [3][64]
                                                const float* __restrict__ b0,
                                                const uint32_t* __restrict__ csr,
                                                const int* __restrict__ offsets,
                                                const int* __restrict__ cnt3,
                                                float* __restrict__ hout) {
  __shared__ float sW[576], sR[192], sb[64];
  int t = threadIdx.x;
  for (int i = t; i < 576; i += 256) sW[i] = W0[i];
  for (int i = t; i < 192; i += 256) sR[i] = root0[i];
  if (t < 64) sb[t] = b0[t];
  __syncthreads();
  int n = blockIdx.x * 256 + t;
  if (n >= N_NODES) return;

  float a00 = 0, a01 = 0, a02 = 0, a10 = 0, a11 = 0, a12 = 0, a20 = 0, a21 = 0, a22 = 0;
  int off = offsets[n];
  int c0 = cnt3[3 * n], c1 = cnt3[3 * n + 1], c2 = cnt3[3 * n + 2];
  int cnt = c0 + c1 + c2;
  for (int i = 0; i < cnt; i++) {
    uint32_t u = csr[off + i];
    int s = u & 0xFFFF;
    int r = u >> 16;
    float v0 = x[s * 3], v1 = x[s * 3 + 1], v2 = x[s * 3 + 2];
    if (r == 0)      { a00 += v0; a01 += v1; a02 += v2; }
    else if (r == 1) { a10 += v0; a11 += v1; a12 += v2; }
    else             { a20 += v0; a21 += v1; a22 += v2; }
  }
  float i0 = 1.0f / (float)(c0 > 1 ? c0 : 1);
  float i1 = 1.0f / (float)(c1 > 1 ? c1 : 1);
  float i2 = 1.0f / (float)(c2 > 1 ? c2 : 1);
  float in[12];
  in[0] = x[n * 3]; in[1] = x[n * 3 + 1]; in[2] = x[n * 3 + 2];
  in[3] = a00 * i0; in[4] = a01 * i0; in[5] = a02 * i0;
  in[6] = a10 * i1; in[7] = a11 * i1; in[8] = a12 * i1;
  in[9] = a20 * i2; in[10] = a21 * i2; in[11] = a22 * i2;

  #pragma unroll
  for (int jj = 0; jj < 64; jj += 4) {
    float o[4];
    #pragma unroll
    for (int c = 0; c < 4; c++) {
      int j = jj + c;
      float acc = sb[j];
      #pragma unroll
      for (int k = 0; k < 3; k++) acc = fmaf(in[k], sR[k * 64 + j], acc);
      #pragma unroll
      for (int k = 0; k < 9; k++) acc = fmaf(in[3 + k], sW[k * 64 + j], acc);
      o[c] = fmaxf(acc, 0.0f);
    }
    *(float4*)(hout + n * 64 + jj) = make_float4(o[0], o[1], o[2], o[3]);
  }
}

// ---------------------------------------------------------------------------
// Layers 1,2: din=64. One wave (64 lanes) per node; lane = feature dim.
// Wcat rows: 0..63 = root, 64..127 = W[0], 128..191 = W[1], 192..255 = W[2]
// ---------------------------------------------------------------------------
__global__ __launch_bounds__(256) void k_layer(const float* __restrict__ hin,
                                               const float* __restrict__ W,    // [3][64][64]
                                               const float* __restrict__ root, // [64][64]
                                               const float* __restrict__ b,
                                               const uint32_t* __restrict__ csr,
                                               const int* __restrict__ offsets,
                                               const int* __restrict__ cnt3,
                                               float* __restrict__ hout) {
  __shared__ float Wc[256 * 64];
  __shared__ float sb[64];
  __shared__ float stage[4][256];
  int t = threadIdx.x;
  {
    const float4* r4 = (const float4*)root;
    const float4* w4 = (const float4*)W;
    float4* wc4 = (float4*)Wc;
    for (int i = t; i < 1024; i += 256) wc4[i] = r4[i];
    for (int i = t; i < 3072; i += 256) wc4[1024 + i] = w4[i];
    if (t < 64) sb[t] = b[t];
  }
  __syncthreads();
  int wid = t >> 6, lane = t & 63;
  int n = blockIdx.x * 4 + wid;   // grid exact: 12500*4 = 50000

  int off = offsets[n];
  int c0 = cnt3[3 * n], c1 = cnt3[3 * n + 1], c2 = cnt3[3 * n + 2];
  int cnt = c0 + c1 + c2;
  float a0 = 0, a1 = 0, a2 = 0;
  for (int i = 0; i < cnt; i++) {
    uint32_t u = csr[off + i];
    int s = u & 0xFFFF;
    int r = u >> 16;
    float v = hin[s * 64 + lane];
    if (r == 0) a0 += v;
    else if (r == 1) a1 += v;
    else a2 += v;
  }
  float* st = stage[wid];
  st[lane]       = hin[n * 64 + lane];
  st[64 + lane]  = a0 * (1.0f / (float)(c0 > 1 ? c0 : 1));
  st[128 + lane] = a1 * (1.0f / (float)(c1 > 1 ? c1 : 1));
  st[192 + lane] = a2 * (1.0f / (float)(c2 > 1 ? c2 : 1));
  __syncthreads();

  float acc = sb[lane];
  #pragma unroll 32
  for (int k = 0; k < 256; k++) acc = fmaf(st[k], Wc[k * 64 + lane], acc);
  hout[n * 64 + lane] = fmaxf(acc, 0.0f);
}

// ---------------------------------------------------------------------------
// Decoder precompute: P[n] = h[n] @ dw1[0:64] + db1 ; Q[n] = h[n] @ dw1[64:128]
// ---------------------------------------------------------------------------
__global__ __launch_bounds__(256) void k_pq(const float* __restrict__ h,
                                            const float* __restrict__ dw1,  // [134][32]
                                            const float* __restrict__ db1,
                                            float* __restrict__ P,
                                            float* __restrict__ Q) {
  __shared__ float A[64 * 32], B[64 * 32], sb1[32];
  int t = threadIdx.x;
  {
    const float4* a4 = (const float4*)dw1;
    float4* A4 = (float4*)A;
    float4* B4 = (float4*)B;
    for (int i = t; i < 512; i += 256) A4[i] = a4[i];
    for (int i = t; i < 512; i += 256) B4[i] = a4[512 + i];
    if (t < 32) sb1[t] = db1[t];
  }
  __syncthreads();
  int n = blockIdx.x * 256 + t;
  if (n >= N_NODES) return;
  float p[32], q[32];
  #pragma unroll
  for (int j = 0; j < 32; j++) { p[j] = sb1[j]; q[j] = 0.0f; }
  const float4* h4 = (const float4*)(h + n * 64);
  #pragma unroll
  for (int k4 = 0; k4 < 16; k4++) {
    float4 v = h4[k4];
    #pragma unroll
    for (int c = 0; c < 4; c++) {
      float hv = (&v.x)[c];
      int k = k4 * 4 + c;
      #pragma unroll
      for (int j = 0; j < 32; j++) {
        p[j] = fmaf(hv, A[k * 32 + j], p[j]);
        q[j] = fmaf(hv, B[k * 32 + j], q[j]);
      }
    }
  }
  float4* P4 = (float4*)(P + n * 32);
  float4* Q4 = (float4*)(Q + n * 32);
  #pragma unroll
  for (int j4 = 0; j4 < 8; j4++) {
    P4[j4] = make_float4(p[4 * j4], p[4 * j4 + 1], p[4 * j4 + 2], p[4 * j4 + 3]);
    Q4[j4] = make_float4(q[4 * j4], q[4 * j4 + 1], q[4 * j4 + 2], q[4 * j4 + 3]);
  }
}

// ---------------------------------------------------------------------------
// Decoder edge pass: out = relu(relu(P[s]+Q[d]+ea@C) @ dw2 + db2) @ dw3 + db3
// ---------------------------------------------------------------------------
__global__ __launch_bounds__(256) void k_dec(const int* __restrict__ src32,
                                             const int* __restrict__ dstrel,
                                             const float* __restrict__ ea,
                                             const float* __restrict__ P,
                                             const float* __restrict__ Q,
                                             const float* __restrict__ dw1,
                                             const float* __restrict__ dw2,
                                             const float* __restrict__ db2,
                                             const float* __restrict__ dw3,
                                             const float* __restrict__ db3,
                                             float* __restrict__ out) {
  __shared__ float C[6 * 32], W2[32 * 16], sb2[16], W3[16];
  __shared__ float sb3;
  int t = threadIdx.x;
  for (int i = t; i < 192; i += 256) C[i] = dw1[128 * 32 + i];
  for (int i = t; i < 512; i += 256) W2[i] = dw2[i];
  if (t < 16) { sb2[t] = db2[t]; W3[t] = dw3[t]; }
  if (t == 0) sb3 = db3[0];
  __syncthreads();
  int e = blockIdx.x * 256 + t;   // grid exact
  int s = src32[e];
  int d = dstrel[e] & 0xFFFFF;
  float ea6[6];
  #pragma unroll
  for (int i = 0; i < 6; i++) ea6[i] = ea[e * 6 + i];
  const float4* Ps = (const float4*)(P + s * 32);
  const float4* Qd = (const float4*)(Q + d * 32);
  float z1[32];
  #pragma unroll
  for (int j4 = 0; j4 < 8; j4++) {
    float4 pv = Ps[j4];
    float4 qv = Qd[j4];
    #pragma unroll
    for (int c = 0; c < 4; c++) {
      int j = j4 * 4 + c;
      float v = (&pv.x)[c] + (&qv.x)[c];
      #pragma unroll
      for (int k = 0; k < 6; k++) v = fmaf(ea6[k], C[k * 32 + j], v);
      z1[j] = fmaxf(v, 0.0f);
    }
  }
  float o = sb3;
  #pragma unroll
  for (int i = 0; i < 16; i++) {
    float z = sb2[i];
    #pragma unroll
    for (int j = 0; j < 32; j++) z = fmaf(z1[j], W2[j * 16 + i], z);
    o = fmaf(fmaxf(z, 0.0f), W3[i], o);
  }
  out[e] = o;
}

// ---------------------------------------------------------------------------
extern "C" void kernel_launch(void* const* d_in, const int* in_sizes, int n_in,
                              void* d_out, int out_size, void* d_ws, size_t ws_size,
                              hipStream_t stream) {
  const float* x      = (const float*)d_in[0];
  const int*   ei     = (const int*)d_in[1];
  const float* ea     = (const float*)d_in[2];
  const float* w0     = (const float*)d_in[3];
  const float* root0  = (const float*)d_in[4];
  const float* b0     = (const float*)d_in[5];
  const float* w1     = (const float*)d_in[6];
  const float* root1  = (const float*)d_in[7];
  const float* b1     = (const float*)d_in[8];
  const float* w2     = (const float*)d_in[9];
  const float* root2  = (const float*)d_in[10];
  const float* b2     = (const float*)d_in[11];
  const float* dw1    = (const float*)d_in[12];
  const float* db1    = (const float*)d_in[13];
  const float* dw2    = (const float*)d_in[14];
  const float* db2    = (const float*)d_in[15];
  const float* dw3    = (const float*)d_in[16];
  const float* db3    = (const float*)d_in[17];
  float* out = (float*)d_out;

  char* w = (char*)d_ws;
  int* src32       = (int*)w;       w += (size_t)N_EDGES * 4;
  int* dstrel      = (int*)w;       w += (size_t)N_EDGES * 4;
  int* cnt3        = (int*)w;       w += (size_t)N_NODES * 3 * 4;
  int* cursor      = (int*)w;       w += (size_t)N_NODES * 4;   // contiguous after cnt3
  int* offsets     = (int*)w;       w += (size_t)N_NODES * 4;
  uint32_t* csr    = (uint32_t*)w;  w += (size_t)N_EDGES * 4;
  float* h1        = (float*)w;     w += (size_t)N_NODES * HID * 4;
  float* h2        = (float*)w;     w += (size_t)N_NODES * HID * 4;
  float* P         = h2;                       // h2 is dead after layer 2
  float* Q         = h2 + (size_t)N_NODES * 32;

  // zero cnt3 + cursor (contiguous)
  hipMemsetAsync(cnt3, 0, (size_t)(N_NODES * 3 + N_NODES) * 4, stream);

  k_prep<<<N_EDGES / 256, 256, 0, stream>>>(ei, ea, src32, dstrel, cnt3);
  k_scan<<<1, 1024, 0, stream>>>(cnt3, offsets);
  k_scatter<<<N_EDGES / 256, 256, 0, stream>>>(src32, dstrel, offsets, cursor, csr);

  k_layer0<<<(N_NODES + 255) / 256, 256, 0, stream>>>(x, w0, root0, b0, csr, offsets, cnt3, h1);
  k_layer<<<N_NODES / 4, 256, 0, stream>>>(h1, w1, root1, b1, csr, offsets, cnt3, h2);
  // note: layer2 reads h2 -> writes h1; then h2 reused as P/Q
  k_layer<<<N_NODES / 4, 256, 0, stream>>>(h2, w2, root2, b2, csr, offsets, cnt3, h1);

  k_pq<<<(N_NODES + 255) / 256, 256, 0, stream>>>(h1, dw1, db1, P, Q);
  k_dec<<<N_EDGES / 256, 256, 0, stream>>>(src32, dstrel, ea, P, Q, dw1, dw2, db2, dw3, db3, out);
}

// Round 2
// 614.940 us; speedup vs baseline: 2.7225x; 2.7225x over previous
//
#include <hip/hip_runtime.h>
#include <stdint.h>

#define N_NODES 50000
#define N_EDGES 1600000

// ---------------------------------------------------------------------------
// Prep: per-(node,rel) counts
// ---------------------------------------------------------------------------
__global__ __launch_bounds__(256) void k_prep(const int* __restrict__ ei,
                                              const float* __restrict__ ea,
                                              int* __restrict__ cnt3) {
  int e = blockIdx.x * 256 + threadIdx.x;   // grid exact
  float dist = ea[(size_t)e * 6];
  int rel = (dist > 5000.0f) + (dist > 10000.0f);
  int d = ei[N_EDGES + e];
  atomicAdd(&cnt3[d * 3 + rel], 1);
}

// single-block scan of node degrees -> meta {off, c0, c1, c2}
__global__ __launch_bounds__(1024) void k_scan(const int* __restrict__ cnt3,
                                               int4* __restrict__ meta) {
  __shared__ int sums[1024];
  const int CH = 49;  // 1024*49 >= 50000
  int t = threadIdx.x;
  int start = t * CH;
  int local = 0;
  for (int i = 0; i < CH; i++) {
    int n = start + i;
    if (n < N_NODES) local += cnt3[3 * n] + cnt3[3 * n + 1] + cnt3[3 * n + 2];
  }
  sums[t] = local;
  __syncthreads();
  for (int ofs = 1; ofs < 1024; ofs <<= 1) {
    int v = (t >= ofs) ? sums[t - ofs] : 0;
    __syncthreads();
    sums[t] += v;
    __syncthreads();
  }
  int base = (t == 0) ? 0 : sums[t - 1];
  for (int i = 0; i < CH; i++) {
    int n = start + i;
    if (n < N_NODES) {
      int c0 = cnt3[3 * n], c1 = cnt3[3 * n + 1], c2 = cnt3[3 * n + 2];
      meta[n] = make_int4(base, c0, c1, c2);
      base += c0 + c1 + c2;
    }
  }
}

__global__ __launch_bounds__(256) void k_scatter(const int* __restrict__ ei,
                                                 const float* __restrict__ ea,
                                                 const int4* __restrict__ meta,
                                                 int* __restrict__ cursor,
                                                 uint32_t* __restrict__ csr) {
  int e = blockIdx.x * 256 + threadIdx.x;
  float dist = ea[(size_t)e * 6];
  int rel = (dist > 5000.0f) + (dist > 10000.0f);
  int s = ei[e];
  int d = ei[N_EDGES + e];
  int p = meta[d].x + atomicAdd(&cursor[d], 1);
  csr[p] = (uint32_t)s | ((uint32_t)rel << 16);   // src < 65536
}

// pad x to float4 (w=0) so layer-0 gathers are one 16B load
__global__ __launch_bounds__(256) void k_padx(const float* __restrict__ x,
                                              float4* __restrict__ x4) {
  int n = blockIdx.x * 256 + threadIdx.x;
  if (n < N_NODES) x4[n] = make_float4(x[n * 3], x[n * 3 + 1], x[n * 3 + 2], 0.0f);
}

// ---------------------------------------------------------------------------
// Layer 0: din=3. Wave per node, lanes parallel over edges, butterfly reduce.
// ---------------------------------------------------------------------------
__global__ __launch_bounds__(256) void k_layer0(const float4* __restrict__ x4,
                                                const float* __restrict__ W0,    // [3][3][64]
                                                const float* __restrict__ root0, // [3][64]
                                                const float* __restrict__ b0,
                                                const int4* __restrict__ meta,
                                                const uint32_t* __restrict__ csr,
                                                float* __restrict__ hout) {
  __shared__ float sW[576], sR[192], sb[64];
  int t = threadIdx.x;
  for (int i = t; i < 576; i += 256) sW[i] = W0[i];
  for (int i = t; i < 192; i += 256) sR[i] = root0[i];
  if (t < 64) sb[t] = b0[t];
  __syncthreads();
  int wid = t >> 6, lane = t & 63;
  int n = blockIdx.x * 4 + wid;   // grid exact: 12500*4
  int4 md = meta[n];
  int off = md.x, c0 = md.y, c1 = md.z, c2 = md.w;
  int cnt = c0 + c1 + c2;
  float a00 = 0, a01 = 0, a02 = 0, a10 = 0, a11 = 0, a12 = 0, a20 = 0, a21 = 0, a22 = 0;
  for (int base = 0; base < cnt; base += 64) {
    int idx = base + lane;
    float4 v = make_float4(0, 0, 0, 0);
    int r = 3;
    if (idx < cnt) {
      uint32_t u = csr[off + idx];
      r = (int)(u >> 16);
      v = x4[u & 0xFFFFu];
    }
    a00 += (r == 0) ? v.x : 0.0f; a01 += (r == 0) ? v.y : 0.0f; a02 += (r == 0) ? v.z : 0.0f;
    a10 += (r == 1) ? v.x : 0.0f; a11 += (r == 1) ? v.y : 0.0f; a12 += (r == 1) ? v.z : 0.0f;
    a20 += (r == 2) ? v.x : 0.0f; a21 += (r == 2) ? v.y : 0.0f; a22 += (r == 2) ? v.z : 0.0f;
  }
  #pragma unroll
  for (int d = 1; d < 64; d <<= 1) {
    a00 += __shfl_xor(a00, d); a01 += __shfl_xor(a01, d); a02 += __shfl_xor(a02, d);
    a10 += __shfl_xor(a10, d); a11 += __shfl_xor(a11, d); a12 += __shfl_xor(a12, d);
    a20 += __shfl_xor(a20, d); a21 += __shfl_xor(a21, d); a22 += __shfl_xor(a22, d);
  }
  float i0 = 1.0f / (float)(c0 > 1 ? c0 : 1);
  float i1 = 1.0f / (float)(c1 > 1 ? c1 : 1);
  float i2 = 1.0f / (float)(c2 > 1 ? c2 : 1);
  float4 xn = x4[n];
  float in[12];
  in[0] = xn.x; in[1] = xn.y; in[2] = xn.z;
  in[3] = a00 * i0; in[4] = a01 * i0; in[5] = a02 * i0;
  in[6] = a10 * i1; in[7] = a11 * i1; in[8] = a12 * i1;
  in[9] = a20 * i2; in[10] = a21 * i2; in[11] = a22 * i2;
  float acc = sb[lane];
  #pragma unroll
  for (int k = 0; k < 3; k++) acc = fmaf(in[k], sR[k * 64 + lane], acc);
  #pragma unroll
  for (int k = 0; k < 9; k++) acc = fmaf(in[3 + k], sW[k * 64 + lane], acc);
  hout[(size_t)n * 64 + lane] = fmaxf(acc, 0.0f);
}

// ---------------------------------------------------------------------------
// Aggregation (layers 1,2): wave per node, lane = feature. Unroll-8 gather MLP.
// Writes per-rel means to mbuf[n][192].
// ---------------------------------------------------------------------------
#define ACC(E, V) { int r_ = (int)((E) >> 16); \
  a0 += (r_ == 0) ? (V) : 0.0f; a1 += (r_ == 1) ? (V) : 0.0f; a2 += (r_ == 2) ? (V) : 0.0f; }

__global__ __launch_bounds__(256) void k_agg(const float* __restrict__ hin,
                                             const int4* __restrict__ meta,
                                             const uint32_t* __restrict__ csr,
                                             float* __restrict__ mbuf) {
  int t = threadIdx.x, wid = t >> 6, lane = t & 63;
  int n = blockIdx.x * 4 + wid;
  int4 md = meta[n];
  int off = __builtin_amdgcn_readfirstlane(md.x);
  int c0  = __builtin_amdgcn_readfirstlane(md.y);
  int c1  = __builtin_amdgcn_readfirstlane(md.z);
  int c2  = __builtin_amdgcn_readfirstlane(md.w);
  int cnt = c0 + c1 + c2;
  const uint32_t* cp = csr + off;
  float a0 = 0, a1 = 0, a2 = 0;
  int i = 0;
  for (; i + 8 <= cnt; i += 8) {
    uint32_t e0 = cp[i],     e1 = cp[i + 1], e2 = cp[i + 2], e3 = cp[i + 3];
    uint32_t e4 = cp[i + 4], e5 = cp[i + 5], e6 = cp[i + 6], e7 = cp[i + 7];
    float v0 = hin[(int)((e0 & 0xFFFFu) << 6) + lane];
    float v1 = hin[(int)((e1 & 0xFFFFu) << 6) + lane];
    float v2 = hin[(int)((e2 & 0xFFFFu) << 6) + lane];
    float v3 = hin[(int)((e3 & 0xFFFFu) << 6) + lane];
    float v4 = hin[(int)((e4 & 0xFFFFu) << 6) + lane];
    float v5 = hin[(int)((e5 & 0xFFFFu) << 6) + lane];
    float v6 = hin[(int)((e6 & 0xFFFFu) << 6) + lane];
    float v7 = hin[(int)((e7 & 0xFFFFu) << 6) + lane];
    ACC(e0, v0) ACC(e1, v1) ACC(e2, v2) ACC(e3, v3)
    ACC(e4, v4) ACC(e5, v5) ACC(e6, v6) ACC(e7, v7)
  }
  for (; i < cnt; i++) {
    uint32_t e = cp[i];
    float v = hin[(int)((e & 0xFFFFu) << 6) + lane];
    ACC(e, v)
  }
  float* mb = mbuf + (size_t)n * 192;
  mb[lane]       = a0 * (1.0f / (float)(c0 > 1 ? c0 : 1));
  mb[64 + lane]  = a1 * (1.0f / (float)(c1 > 1 ? c1 : 1));
  mb[128 + lane] = a2 * (1.0f / (float)(c2 > 1 ? c2 : 1));
}

// ---------------------------------------------------------------------------
// Transform GEMM: hout[n][j] = relu(b[j] + sum_k A[n][k] * Wcat[k][j])
// A[n][0:64]=hin[n], A[n][64:256]=mbuf[n]. M=50000, N=64, K=256.
// Tile BM=64, BK=64; 256 threads, 4x4 register tile per thread.
// ---------------------------------------------------------------------------
__global__ __launch_bounds__(256) void k_gemm(const float* __restrict__ hin,
                                              const float* __restrict__ mbuf,
                                              const float* __restrict__ W,    // [3][64][64]
                                              const float* __restrict__ root, // [64][64]
                                              const float* __restrict__ b,
                                              float* __restrict__ hout) {
  __shared__ float As[64 * 84];   // row stride 84 floats (16B aligned, conflict-light)
  __shared__ float Bs[64 * 64];
  __shared__ float sb[64];
  int t = threadIdx.x;
  int bn = blockIdx.x * 64;
  if (t < 64) sb[t] = b[t];
  int tn = t & 15, to = t >> 4;   // rows {tn+16i}, cols to*4..to*4+3
  float acc[4][4] = {};
  for (int kb = 0; kb < 4; kb++) {
    const float4* Bsrc = (const float4*)((kb == 0) ? root : (W + (size_t)(kb - 1) * 4096));
    for (int i2 = t; i2 < 1024; i2 += 256) ((float4*)Bs)[i2] = Bsrc[i2];
    int r = t >> 2;
    int node = bn + r;
    bool ok = node < N_NODES;
    const float* Arow = (kb == 0) ? (hin + (size_t)node * 64)
                                  : (mbuf + (size_t)node * 192 + (size_t)(kb - 1) * 64);
    #pragma unroll
    for (int ii = 0; ii < 4; ii++) {
      int c4 = (t & 3) + 4 * ii;
      float4 v = ok ? ((const float4*)Arow)[c4] : make_float4(0, 0, 0, 0);
      *(float4*)&As[r * 84 + c4 * 4] = v;
    }
    __syncthreads();
    #pragma unroll
    for (int k4 = 0; k4 < 16; k4++) {
      float4 a0 = *(const float4*)&As[(tn)      * 84 + k4 * 4];
      float4 a1 = *(const float4*)&As[(tn + 16) * 84 + k4 * 4];
      float4 a2 = *(const float4*)&As[(tn + 32) * 84 + k4 * 4];
      float4 a3 = *(const float4*)&As[(tn + 48) * 84 + k4 * 4];
      float4 b0 = *(const float4*)&Bs[(k4 * 4 + 0) * 64 + to * 4];
      float4 b1 = *(const float4*)&Bs[(k4 * 4 + 1) * 64 + to * 4];
      float4 b2 = *(const float4*)&Bs[(k4 * 4 + 2) * 64 + to * 4];
      float4 b3 = *(const float4*)&Bs[(k4 * 4 + 3) * 64 + to * 4];
      const float* av[4] = {&a0.x, &a1.x, &a2.x, &a3.x};
      const float* bv[4] = {&b0.x, &b1.x, &b2.x, &b3.x};
      #pragma unroll
      for (int c = 0; c < 4; c++)
        #pragma unroll
        for (int i3 = 0; i3 < 4; i3++)
          #pragma unroll
          for (int j = 0; j < 4; j++)
            acc[i3][j] = fmaf(av[i3][c], bv[c][j], acc[i3][j]);
    }
    __syncthreads();
  }
  #pragma unroll
  for (int i3 = 0; i3 < 4; i3++) {
    int node = bn + tn + 16 * i3;
    if (node < N_NODES) {
      float4 o;
      o.x = fmaxf(acc[i3][0] + sb[to * 4 + 0], 0.0f);
      o.y = fmaxf(acc[i3][1] + sb[to * 4 + 1], 0.0f);
      o.z = fmaxf(acc[i3][2] + sb[to * 4 + 2], 0.0f);
      o.w = fmaxf(acc[i3][3] + sb[to * 4 + 3], 0.0f);
      *(float4*)(hout + (size_t)node * 64 + to * 4) = o;
    }
  }
}

// ---------------------------------------------------------------------------
// Decoder precompute: P[n] = h[n] @ dw1[0:64] + db1 ; Q[n] = h[n] @ dw1[64:128]
// ---------------------------------------------------------------------------
__global__ __launch_bounds__(256) void k_pq(const float* __restrict__ h,
                                            const float* __restrict__ dw1,  // [134][32]
                                            const float* __restrict__ db1,
                                            float* __restrict__ P,
                                            float* __restrict__ Q) {
  __shared__ float A[64 * 32], B[64 * 32], sb1[32];
  int t = threadIdx.x;
  {
    const float4* a4 = (const float4*)dw1;
    float4* A4 = (float4*)A;
    float4* B4 = (float4*)B;
    for (int i = t; i < 512; i += 256) A4[i] = a4[i];
    for (int i = t; i < 512; i += 256) B4[i] = a4[512 + i];
    if (t < 32) sb1[t] = db1[t];
  }
  __syncthreads();
  int n = blockIdx.x * 256 + t;
  if (n >= N_NODES) return;
  float p[32], q[32];
  #pragma unroll
  for (int j = 0; j < 32; j++) { p[j] = sb1[j]; q[j] = 0.0f; }
  const float4* h4 = (const float4*)(h + (size_t)n * 64);
  #pragma unroll
  for (int k4 = 0; k4 < 16; k4++) {
    float4 v = h4[k4];
    #pragma unroll
    for (int c = 0; c < 4; c++) {
      float hv = (&v.x)[c];
      int k = k4 * 4 + c;
      #pragma unroll
      for (int j = 0; j < 32; j++) {
        p[j] = fmaf(hv, A[k * 32 + j], p[j]);
        q[j] = fmaf(hv, B[k * 32 + j], q[j]);
      }
    }
  }
  float4* P4 = (float4*)(P + (size_t)n * 32);
  float4* Q4 = (float4*)(Q + (size_t)n * 32);
  #pragma unroll
  for (int j4 = 0; j4 < 8; j4++) {
    P4[j4] = make_float4(p[4 * j4], p[4 * j4 + 1], p[4 * j4 + 2], p[4 * j4 + 3]);
    Q4[j4] = make_float4(q[4 * j4], q[4 * j4 + 1], q[4 * j4 + 2], q[4 * j4 + 3]);
  }
}

// ---------------------------------------------------------------------------
// Decoder edge pass
// ---------------------------------------------------------------------------
__global__ __launch_bounds__(256) void k_dec(const int* __restrict__ ei,
                                             const float* __restrict__ ea,
                                             const float* __restrict__ P,
                                             const float* __restrict__ Q,
                                             const float* __restrict__ dw1,
                                             const float* __restrict__ dw2,
                                             const float* __restrict__ db2,
                                             const float* __restrict__ dw3,
                                             const float* __restrict__ db3,
                                             float* __restrict__ out) {
  __shared__ float C[6 * 32], W2[32 * 16], sb2[16], W3[16];
  __shared__ float sb3;
  int t = threadIdx.x;
  for (int i = t; i < 192; i += 256) C[i] = dw1[128 * 32 + i];
  for (int i = t; i < 512; i += 256) W2[i] = dw2[i];
  if (t < 16) { sb2[t] = db2[t]; W3[t] = dw3[t]; }
  if (t == 0) sb3 = db3[0];
  __syncthreads();
  int e = blockIdx.x * 256 + t;   // grid exact
  int s = ei[e];
  int d = ei[N_EDGES + e];
  float ea6[6];
  #pragma unroll
  for (int i = 0; i < 6; i++) ea6[i] = ea[(size_t)e * 6 + i];
  const float4* Ps = (const float4*)(P + (size_t)s * 32);
  const float4* Qd = (const float4*)(Q + (size_t)d * 32);
  float z1[32];
  #pragma unroll
  for (int j4 = 0; j4 < 8; j4++) {
    float4 pv = Ps[j4];
    float4 qv = Qd[j4];
    #pragma unroll
    for (int c = 0; c < 4; c++) {
      int j = j4 * 4 + c;
      float v = (&pv.x)[c] + (&qv.x)[c];
      #pragma unroll
      for (int k = 0; k < 6; k++) v = fmaf(ea6[k], C[k * 32 + j], v);
      z1[j] = fmaxf(v, 0.0f);
    }
  }
  float o = sb3;
  #pragma unroll
  for (int i = 0; i < 16; i++) {
    float z = sb2[i];
    #pragma unroll
    for (int j = 0; j < 32; j++) z = fmaf(z1[j], W2[j * 16 + i], z);
    o = fmaf(fmaxf(z, 0.0f), W3[i], o);
  }
  out[e] = o;
}

// ---------------------------------------------------------------------------
extern "C" void kernel_launch(void* const* d_in, const int* in_sizes, int n_in,
                              void* d_out, int out_size, void* d_ws, size_t ws_size,
                              hipStream_t stream) {
  const float* x      = (const float*)d_in[0];
  const int*   ei     = (const int*)d_in[1];
  const float* ea     = (const float*)d_in[2];
  const float* w0     = (const float*)d_in[3];
  const float* root0  = (const float*)d_in[4];
  const float* b0     = (const float*)d_in[5];
  const float* w1     = (const float*)d_in[6];
  const float* root1  = (const float*)d_in[7];
  const float* b1     = (const float*)d_in[8];
  const float* w2     = (const float*)d_in[9];
  const float* root2  = (const float*)d_in[10];
  const float* b2     = (const float*)d_in[11];
  const float* dw1    = (const float*)d_in[12];
  const float* db1    = (const float*)d_in[13];
  const float* dw2    = (const float*)d_in[14];
  const float* db2    = (const float*)d_in[15];
  const float* dw3    = (const float*)d_in[16];
  const float* db3    = (const float*)d_in[17];
  float* out = (float*)d_out;

  char* w = (char*)d_ws;
  int* cnt3        = (int*)w;       w += (size_t)N_NODES * 3 * 4;
  int* cursor      = (int*)w;       w += (size_t)N_NODES * 4;     // contiguous after cnt3
  int4* meta       = (int4*)w;      w += (size_t)N_NODES * 16;
  uint32_t* csr    = (uint32_t*)w;  w += (size_t)N_EDGES * 4;
  float4* x4       = (float4*)w;    w += (size_t)N_NODES * 16;
  float* h1        = (float*)w;     w += (size_t)N_NODES * 64 * 4;
  float* h2        = (float*)w;     w += (size_t)N_NODES * 64 * 4;
  float* mbuf      = (float*)w;     w += (size_t)N_NODES * 192 * 4;
  float* P         = mbuf;                      // mbuf dead after layers
  float* Q         = mbuf + (size_t)N_NODES * 32;

  hipMemsetAsync(cnt3, 0, (size_t)(N_NODES * 3 + N_NODES) * 4, stream);

  k_prep   <<<N_EDGES / 256, 256, 0, stream>>>(ei, ea, cnt3);
  k_scan   <<<1, 1024, 0, stream>>>(cnt3, meta);
  k_scatter<<<N_EDGES / 256, 256, 0, stream>>>(ei, ea, meta, cursor, csr);
  k_padx   <<<(N_NODES + 255) / 256, 256, 0, stream>>>(x, x4);

  k_layer0 <<<N_NODES / 4, 256, 0, stream>>>(x4, w0, root0, b0, meta, csr, h1);

  k_agg    <<<N_NODES / 4, 256, 0, stream>>>(h1, meta, csr, mbuf);
  k_gemm   <<<(N_NODES + 63) / 64, 256, 0, stream>>>(h1, mbuf, w1, root1, b1, h2);

  k_agg    <<<N_NODES / 4, 256, 0, stream>>>(h2, meta, csr, mbuf);
  k_gemm   <<<(N_NODES + 63) / 64, 256, 0, stream>>>(h2, mbuf, w2, root2, b2, h1);

  k_pq     <<<(N_NODES + 255) / 256, 256, 0, stream>>>(h1, dw1, db1, P, Q);
  k_dec    <<<N_EDGES / 256, 256, 0, stream>>>(ei, ea, P, Q, dw1, dw2, db2, dw3, db3, out);
}

// Round 3
// 517.690 us; speedup vs baseline: 3.2340x; 1.1879x over previous
//
#include <hip/hip_runtime.h>
#include <stdint.h>

#define N_NODES 50000
#define N_EDGES 1600000
#define NBLK_N 196   // ceil(50000/256)

// ---------------------------------------------------------------------------
// Prep: per-(node,rel) counts + packed src|rel word (the final CSR payload)
// ---------------------------------------------------------------------------
__global__ __launch_bounds__(256) void k_prep(const int* __restrict__ ei,
                                              const float* __restrict__ ea,
                                              int* __restrict__ cnt3,
                                              uint32_t* __restrict__ srcrel) {
  int e = blockIdx.x * 256 + threadIdx.x;   // grid exact
  float dist = ea[(size_t)e * 6];
  int rel = (dist > 5000.0f) + (dist > 10000.0f);
  int s = ei[e];
  int d = ei[N_EDGES + e];
  srcrel[e] = (uint32_t)s | ((uint32_t)rel << 16);   // src < 65536
  atomicAdd(&cnt3[d * 3 + rel], 1);
}

// ---------------------------------------------------------------------------
// Parallel scan of node degrees: A) per-block scan, B) scan block sums,
// C) build meta {off,c0,c1,c2} (+ fused x->x4 padding)
// ---------------------------------------------------------------------------
__global__ __launch_bounds__(256) void k_scanA(const int* __restrict__ cnt3,
                                               int* __restrict__ excl,
                                               int* __restrict__ bsum) {
  __shared__ int s[256];
  int t = threadIdx.x;
  int n = blockIdx.x * 256 + t;
  int deg = 0;
  if (n < N_NODES) deg = cnt3[3 * n] + cnt3[3 * n + 1] + cnt3[3 * n + 2];
  s[t] = deg;
  __syncthreads();
  for (int ofs = 1; ofs < 256; ofs <<= 1) {
    int v = (t >= ofs) ? s[t - ofs] : 0;
    __syncthreads();
    s[t] += v;
    __syncthreads();
  }
  if (n < N_NODES) excl[n] = s[t] - deg;
  if (t == 255) bsum[blockIdx.x] = s[255];
}

__global__ __launch_bounds__(256) void k_scanB(int* __restrict__ bsum) {
  __shared__ int s[256];
  int t = threadIdx.x;
  int v = (t < NBLK_N) ? bsum[t] : 0;
  s[t] = v;
  __syncthreads();
  for (int ofs = 1; ofs < 256; ofs <<= 1) {
    int u = (t >= ofs) ? s[t - ofs] : 0;
    __syncthreads();
    s[t] += u;
    __syncthreads();
  }
  if (t < NBLK_N) bsum[t] = s[t] - v;   // exclusive
}

__global__ __launch_bounds__(256) void k_scanC(const int* __restrict__ cnt3,
                                               const int* __restrict__ excl,
                                               const int* __restrict__ bsum,
                                               int4* __restrict__ meta,
                                               const float* __restrict__ x,
                                               float4* __restrict__ x4) {
  int n = blockIdx.x * 256 + threadIdx.x;
  if (n >= N_NODES) return;
  meta[n] = make_int4(bsum[blockIdx.x] + excl[n],
                      cnt3[3 * n], cnt3[3 * n + 1], cnt3[3 * n + 2]);
  x4[n] = make_float4(x[n * 3], x[n * 3 + 1], x[n * 3 + 2], 0.0f);
}

__global__ __launch_bounds__(256) void k_scatter(const int* __restrict__ ei,
                                                 const uint32_t* __restrict__ srcrel,
                                                 const int4* __restrict__ meta,
                                                 int* __restrict__ cursor,
                                                 uint32_t* __restrict__ csr) {
  int e = blockIdx.x * 256 + threadIdx.x;
  int d = ei[N_EDGES + e];
  int p = meta[d].x + atomicAdd(&cursor[d], 1);
  csr[p] = srcrel[e];
}

// ---------------------------------------------------------------------------
// Layer 0: din=3. Wave per node, lanes parallel over edges, butterfly reduce.
// ---------------------------------------------------------------------------
__global__ __launch_bounds__(256) void k_layer0(const float4* __restrict__ x4,
                                                const float* __restrict__ W0,    // [3][3][64]
                                                const float* __restrict__ root0, // [3][64]
                                                const float* __restrict__ b0,
                                                const int4* __restrict__ meta,
                                                const uint32_t* __restrict__ csr,
                                                float* __restrict__ hout) {
  __shared__ float sW[576], sR[192], sb[64];
  int t = threadIdx.x;
  for (int i = t; i < 576; i += 256) sW[i] = W0[i];
  for (int i = t; i < 192; i += 256) sR[i] = root0[i];
  if (t < 64) sb[t] = b0[t];
  __syncthreads();
  int wid = t >> 6, lane = t & 63;
  int n = blockIdx.x * 4 + wid;   // grid exact: 12500*4
  int4 md = meta[n];
  int off = md.x, c0 = md.y, c1 = md.z, c2 = md.w;
  int cnt = c0 + c1 + c2;
  float a00 = 0, a01 = 0, a02 = 0, a10 = 0, a11 = 0, a12 = 0, a20 = 0, a21 = 0, a22 = 0;
  for (int base = 0; base < cnt; base += 64) {
    int idx = base + lane;
    float4 v = make_float4(0, 0, 0, 0);
    int r = 3;
    if (idx < cnt) {
      uint32_t u = csr[off + idx];
      r = (int)(u >> 16);
      v = x4[u & 0xFFFFu];
    }
    a00 += (r == 0) ? v.x : 0.0f; a01 += (r == 0) ? v.y : 0.0f; a02 += (r == 0) ? v.z : 0.0f;
    a10 += (r == 1) ? v.x : 0.0f; a11 += (r == 1) ? v.y : 0.0f; a12 += (r == 1) ? v.z : 0.0f;
    a20 += (r == 2) ? v.x : 0.0f; a21 += (r == 2) ? v.y : 0.0f; a22 += (r == 2) ? v.z : 0.0f;
  }
  #pragma unroll
  for (int d = 1; d < 64; d <<= 1) {
    a00 += __shfl_xor(a00, d); a01 += __shfl_xor(a01, d); a02 += __shfl_xor(a02, d);
    a10 += __shfl_xor(a10, d); a11 += __shfl_xor(a11, d); a12 += __shfl_xor(a12, d);
    a20 += __shfl_xor(a20, d); a21 += __shfl_xor(a21, d); a22 += __shfl_xor(a22, d);
  }
  float i0 = 1.0f / (float)(c0 > 1 ? c0 : 1);
  float i1 = 1.0f / (float)(c1 > 1 ? c1 : 1);
  float i2 = 1.0f / (float)(c2 > 1 ? c2 : 1);
  float4 xn = x4[n];
  float in[12];
  in[0] = xn.x; in[1] = xn.y; in[2] = xn.z;
  in[3] = a00 * i0; in[4] = a01 * i0; in[5] = a02 * i0;
  in[6] = a10 * i1; in[7] = a11 * i1; in[8] = a12 * i1;
  in[9] = a20 * i2; in[10] = a21 * i2; in[11] = a22 * i2;
  float acc = sb[lane];
  #pragma unroll
  for (int k = 0; k < 3; k++) acc = fmaf(in[k], sR[k * 64 + lane], acc);
  #pragma unroll
  for (int k = 0; k < 9; k++) acc = fmaf(in[3 + k], sW[k * 64 + lane], acc);
  hout[(size_t)n * 64 + lane] = fmaxf(acc, 0.0f);
}

// ---------------------------------------------------------------------------
// Aggregation (layers 1,2): wave per node, lane = feature. Unroll-8 gather MLP.
// ---------------------------------------------------------------------------
#define ACC(E, V) { int r_ = (int)((E) >> 16); \
  a0 += (r_ == 0) ? (V) : 0.0f; a1 += (r_ == 1) ? (V) : 0.0f; a2 += (r_ == 2) ? (V) : 0.0f; }

__global__ __launch_bounds__(256) void k_agg(const float* __restrict__ hin,
                                             const int4* __restrict__ meta,
                                             const uint32_t* __restrict__ csr,
                                             float* __restrict__ mbuf) {
  int t = threadIdx.x, wid = t >> 6, lane = t & 63;
  int n = blockIdx.x * 4 + wid;
  int4 md = meta[n];
  int off = __builtin_amdgcn_readfirstlane(md.x);
  int c0  = __builtin_amdgcn_readfirstlane(md.y);
  int c1  = __builtin_amdgcn_readfirstlane(md.z);
  int c2  = __builtin_amdgcn_readfirstlane(md.w);
  int cnt = c0 + c1 + c2;
  const uint32_t* cp = csr + off;
  float a0 = 0, a1 = 0, a2 = 0;
  int i = 0;
  for (; i + 8 <= cnt; i += 8) {
    uint32_t e0 = cp[i],     e1 = cp[i + 1], e2 = cp[i + 2], e3 = cp[i + 3];
    uint32_t e4 = cp[i + 4], e5 = cp[i + 5], e6 = cp[i + 6], e7 = cp[i + 7];
    float v0 = hin[(int)((e0 & 0xFFFFu) << 6) + lane];
    float v1 = hin[(int)((e1 & 0xFFFFu) << 6) + lane];
    float v2 = hin[(int)((e2 & 0xFFFFu) << 6) + lane];
    float v3 = hin[(int)((e3 & 0xFFFFu) << 6) + lane];
    float v4 = hin[(int)((e4 & 0xFFFFu) << 6) + lane];
    float v5 = hin[(int)((e5 & 0xFFFFu) << 6) + lane];
    float v6 = hin[(int)((e6 & 0xFFFFu) << 6) + lane];
    float v7 = hin[(int)((e7 & 0xFFFFu) << 6) + lane];
    ACC(e0, v0) ACC(e1, v1) ACC(e2, v2) ACC(e3, v3)
    ACC(e4, v4) ACC(e5, v5) ACC(e6, v6) ACC(e7, v7)
  }
  for (; i < cnt; i++) {
    uint32_t e = cp[i];
    float v = hin[(int)((e & 0xFFFFu) << 6) + lane];
    ACC(e, v)
  }
  float* mb = mbuf + (size_t)n * 192;
  mb[lane]       = a0 * (1.0f / (float)(c0 > 1 ? c0 : 1));
  mb[64 + lane]  = a1 * (1.0f / (float)(c1 > 1 ? c1 : 1));
  mb[128 + lane] = a2 * (1.0f / (float)(c2 > 1 ? c2 : 1));
}

// ---------------------------------------------------------------------------
// Transform GEMM: hout[n][j] = relu(b[j] + sum_k A[n][k] * Wcat[k][j])
// ---------------------------------------------------------------------------
__global__ __launch_bounds__(256) void k_gemm(const float* __restrict__ hin,
                                              const float* __restrict__ mbuf,
                                              const float* __restrict__ W,    // [3][64][64]
                                              const float* __restrict__ root, // [64][64]
                                              const float* __restrict__ b,
                                              float* __restrict__ hout) {
  __shared__ float As[64 * 84];
  __shared__ float Bs[64 * 64];
  __shared__ float sb[64];
  int t = threadIdx.x;
  int bn = blockIdx.x * 64;
  if (t < 64) sb[t] = b[t];
  int tn = t & 15, to = t >> 4;
  float acc[4][4] = {};
  for (int kb = 0; kb < 4; kb++) {
    const float4* Bsrc = (const float4*)((kb == 0) ? root : (W + (size_t)(kb - 1) * 4096));
    for (int i2 = t; i2 < 1024; i2 += 256) ((float4*)Bs)[i2] = Bsrc[i2];
    int r = t >> 2;
    int node = bn + r;
    bool ok = node < N_NODES;
    const float* Arow = (kb == 0) ? (hin + (size_t)node * 64)
                                  : (mbuf + (size_t)node * 192 + (size_t)(kb - 1) * 64);
    #pragma unroll
    for (int ii = 0; ii < 4; ii++) {
      int c4 = (t & 3) + 4 * ii;
      float4 v = ok ? ((const float4*)Arow)[c4] : make_float4(0, 0, 0, 0);
      *(float4*)&As[r * 84 + c4 * 4] = v;
    }
    __syncthreads();
    #pragma unroll
    for (int k4 = 0; k4 < 16; k4++) {
      float4 a0 = *(const float4*)&As[(tn)      * 84 + k4 * 4];
      float4 a1 = *(const float4*)&As[(tn + 16) * 84 + k4 * 4];
      float4 a2 = *(const float4*)&As[(tn + 32) * 84 + k4 * 4];
      float4 a3 = *(const float4*)&As[(tn + 48) * 84 + k4 * 4];
      float4 b0 = *(const float4*)&Bs[(k4 * 4 + 0) * 64 + to * 4];
      float4 b1 = *(const float4*)&Bs[(k4 * 4 + 1) * 64 + to * 4];
      float4 b2 = *(const float4*)&Bs[(k4 * 4 + 2) * 64 + to * 4];
      float4 b3 = *(const float4*)&Bs[(k4 * 4 + 3) * 64 + to * 4];
      const float* av[4] = {&a0.x, &a1.x, &a2.x, &a3.x};
      const float* bv[4] = {&b0.x, &b1.x, &b2.x, &b3.x};
      #pragma unroll
      for (int c = 0; c < 4; c++)
        #pragma unroll
        for (int i3 = 0; i3 < 4; i3++)
          #pragma unroll
          for (int j = 0; j < 4; j++)
            acc[i3][j] = fmaf(av[i3][c], bv[c][j], acc[i3][j]);
    }
    __syncthreads();
  }
  #pragma unroll
  for (int i3 = 0; i3 < 4; i3++) {
    int node = bn + tn + 16 * i3;
    if (node < N_NODES) {
      float4 o;
      o.x = fmaxf(acc[i3][0] + sb[to * 4 + 0], 0.0f);
      o.y = fmaxf(acc[i3][1] + sb[to * 4 + 1], 0.0f);
      o.z = fmaxf(acc[i3][2] + sb[to * 4 + 2], 0.0f);
      o.w = fmaxf(acc[i3][3] + sb[to * 4 + 3], 0.0f);
      *(float4*)(hout + (size_t)node * 64 + to * 4) = o;
    }
  }
}

// ---------------------------------------------------------------------------
// Decoder precompute: P[n] = h[n] @ dw1[0:64] + db1 ; Q[n] = h[n] @ dw1[64:128]
// ---------------------------------------------------------------------------
__global__ __launch_bounds__(256) void k_pq(const float* __restrict__ h,
                                            const float* __restrict__ dw1,
                                            const float* __restrict__ db1,
                                            float* __restrict__ P,
                                            float* __restrict__ Q) {
  __shared__ float A[64 * 32], B[64 * 32], sb1[32];
  int t = threadIdx.x;
  {
    const float4* a4 = (const float4*)dw1;
    float4* A4 = (float4*)A;
    float4* B4 = (float4*)B;
    for (int i = t; i < 512; i += 256) A4[i] = a4[i];
    for (int i = t; i < 512; i += 256) B4[i] = a4[512 + i];
    if (t < 32) sb1[t] = db1[t];
  }
  __syncthreads();
  int n = blockIdx.x * 256 + t;
  if (n >= N_NODES) return;
  float p[32], q[32];
  #pragma unroll
  for (int j = 0; j < 32; j++) { p[j] = sb1[j]; q[j] = 0.0f; }
  const float4* h4 = (const float4*)(h + (size_t)n * 64);
  #pragma unroll
  for (int k4 = 0; k4 < 16; k4++) {
    float4 v = h4[k4];
    #pragma unroll
    for (int c = 0; c < 4; c++) {
      float hv = (&v.x)[c];
      int k = k4 * 4 + c;
      #pragma unroll
      for (int j = 0; j < 32; j++) {
        p[j] = fmaf(hv, A[k * 32 + j], p[j]);
        q[j] = fmaf(hv, B[k * 32 + j], q[j]);
      }
    }
  }
  float4* P4 = (float4*)(P + (size_t)n * 32);
  float4* Q4 = (float4*)(Q + (size_t)n * 32);
  #pragma unroll
  for (int j4 = 0; j4 < 8; j4++) {
    P4[j4] = make_float4(p[4 * j4], p[4 * j4 + 1], p[4 * j4 + 2], p[4 * j4 + 3]);
    Q4[j4] = make_float4(q[4 * j4], q[4 * j4 + 1], q[4 * j4 + 2], q[4 * j4 + 3]);
  }
}

// ---------------------------------------------------------------------------
// Decoder edge pass
// ---------------------------------------------------------------------------
__global__ __launch_bounds__(256) void k_dec(const int* __restrict__ ei,
                                             const float* __restrict__ ea,
                                             const float* __restrict__ P,
                                             const float* __restrict__ Q,
                                             const float* __restrict__ dw1,
                                             const float* __restrict__ dw2,
                                             const float* __restrict__ db2,
                                             const float* __restrict__ dw3,
                                             const float* __restrict__ db3,
                                             float* __restrict__ out) {
  __shared__ float C[6 * 32], W2[32 * 16], sb2[16], W3[16];
  __shared__ float sb3;
  int t = threadIdx.x;
  for (int i = t; i < 192; i += 256) C[i] = dw1[128 * 32 + i];
  for (int i = t; i < 512; i += 256) W2[i] = dw2[i];
  if (t < 16) { sb2[t] = db2[t]; W3[t] = dw3[t]; }
  if (t == 0) sb3 = db3[0];
  __syncthreads();
  int e = blockIdx.x * 256 + t;
  int s = ei[e];
  int d = ei[N_EDGES + e];
  float ea6[6];
  #pragma unroll
  for (int i = 0; i < 6; i++) ea6[i] = ea[(size_t)e * 6 + i];
  const float4* Ps = (const float4*)(P + (size_t)s * 32);
  const float4* Qd = (const float4*)(Q + (size_t)d * 32);
  float z1[32];
  #pragma unroll
  for (int j4 = 0; j4 < 8; j4++) {
    float4 pv = Ps[j4];
    float4 qv = Qd[j4];
    #pragma unroll
    for (int c = 0; c < 4; c++) {
      int j = j4 * 4 + c;
      float v = (&pv.x)[c] + (&qv.x)[c];
      #pragma unroll
      for (int k = 0; k < 6; k++) v = fmaf(ea6[k], C[k * 32 + j], v);
      z1[j] = fmaxf(v, 0.0f);
    }
  }
  float o = sb3;
  #pragma unroll
  for (int i = 0; i < 16; i++) {
    float z = sb2[i];
    #pragma unroll
    for (int j = 0; j < 32; j++) z = fmaf(z1[j], W2[j * 16 + i], z);
    o = fmaf(fmaxf(z, 0.0f), W3[i], o);
  }
  out[e] = o;
}

// ---------------------------------------------------------------------------
extern "C" void kernel_launch(void* const* d_in, const int* in_sizes, int n_in,
                              void* d_out, int out_size, void* d_ws, size_t ws_size,
                              hipStream_t stream) {
  const float* x      = (const float*)d_in[0];
  const int*   ei     = (const int*)d_in[1];
  const float* ea     = (const float*)d_in[2];
  const float* w0     = (const float*)d_in[3];
  const float* root0  = (const float*)d_in[4];
  const float* b0     = (const float*)d_in[5];
  const float* w1     = (const float*)d_in[6];
  const float* root1  = (const float*)d_in[7];
  const float* b1     = (const float*)d_in[8];
  const float* w2     = (const float*)d_in[9];
  const float* root2  = (const float*)d_in[10];
  const float* b2     = (const float*)d_in[11];
  const float* dw1    = (const float*)d_in[12];
  const float* db1    = (const float*)d_in[13];
  const float* dw2    = (const float*)d_in[14];
  const float* db2    = (const float*)d_in[15];
  const float* dw3    = (const float*)d_in[16];
  const float* db3    = (const float*)d_in[17];
  float* out = (float*)d_out;

  char* w = (char*)d_ws;
  int* cnt3        = (int*)w;       w += (size_t)N_NODES * 3 * 4;
  int* cursor      = (int*)w;       w += (size_t)N_NODES * 4;     // contiguous after cnt3
  int4* meta       = (int4*)w;      w += (size_t)N_NODES * 16;
  uint32_t* csr    = (uint32_t*)w;  w += (size_t)N_EDGES * 4;
  float4* x4       = (float4*)w;    w += (size_t)N_NODES * 16;
  float* h1        = (float*)w;     w += (size_t)N_NODES * 64 * 4;
  float* h2        = (float*)w;     w += (size_t)N_NODES * 64 * 4;
  float* mbuf      = (float*)w;     w += (size_t)N_NODES * 192 * 4;
  float* P         = mbuf;                      // mbuf dead after layers
  float* Q         = mbuf + (size_t)N_NODES * 32;
  // srcrel/excl/bsum alias h1/h2 (dead until k_layer0/k_gemm write them)
  uint32_t* srcrel = (uint32_t*)h1;             // 6.4 MB, dead after k_scatter
  int* excl        = (int*)h2;                  // 0.2 MB, dead after k_scanC
  int* bsum        = (int*)h2 + N_NODES;        // 256 ints

  hipMemsetAsync(cnt3, 0, (size_t)(N_NODES * 3 + N_NODES) * 4, stream);

  k_prep   <<<N_EDGES / 256, 256, 0, stream>>>(ei, ea, cnt3, srcrel);
  k_scanA  <<<NBLK_N, 256, 0, stream>>>(cnt3, excl, bsum);
  k_scanB  <<<1, 256, 0, stream>>>(bsum);
  k_scanC  <<<NBLK_N, 256, 0, stream>>>(cnt3, excl, bsum, meta, x, x4);
  k_scatter<<<N_EDGES / 256, 256, 0, stream>>>(ei, srcrel, meta, cursor, csr);

  k_layer0 <<<N_NODES / 4, 256, 0, stream>>>(x4, w0, root0, b0, meta, csr, h1);

  k_agg    <<<N_NODES / 4, 256, 0, stream>>>(h1, meta, csr, mbuf);
  k_gemm   <<<(N_NODES + 63) / 64, 256, 0, stream>>>(h1, mbuf, w1, root1, b1, h2);

  k_agg    <<<N_NODES / 4, 256, 0, stream>>>(h2, meta, csr, mbuf);
  k_gemm   <<<(N_NODES + 63) / 64, 256, 0, stream>>>(h2, mbuf, w2, root2, b2, h1);

  k_pq     <<<(N_NODES + 255) / 256, 256, 0, stream>>>(h1, dw1, db1, P, Q);
  k_dec    <<<N_EDGES / 256, 256, 0, stream>>>(ei, ea, P, Q, dw1, dw2, db2, dw3, db3, out);
}

// Round 4
// 516.794 us; speedup vs baseline: 3.2396x; 1.0017x over previous
//
#include <hip/hip_runtime.h>
#include <stdint.h>

#define N_NODES 50000
#define N_EDGES 1600000
#define NBLK_N 196        // ceil(50000/256)
#define NB 391            // buckets of 128 dst nodes: ceil(50000/128)
#define BPAD 8192         // padded bucket capacity (mean fill 4096, sd ~64)
#define CHUNK 2048        // edges per prep workgroup
#define NWG_PREP 782      // ceil(1.6M/2048)

// ---------------------------------------------------------------------------
// Prep + pass-1 binning: per-(node,rel) counts, pack src|rel|dstLow,
// bin into 391 dst-buckets with per-WG reservations (line-local writes).
// ---------------------------------------------------------------------------
__global__ __launch_bounds__(256) void k_prep(const int* __restrict__ ei,
                                              const float* __restrict__ ea,
                                              int* __restrict__ cnt3,
                                              int* __restrict__ bcur,
                                              uint32_t* __restrict__ pairbuf) {
  __shared__ int hist[NB];
  __shared__ int hbase[NB];
  int t = threadIdx.x;
  int base = blockIdx.x * CHUNK;
  for (int i = t; i < NB; i += 256) hist[i] = 0;
  __syncthreads();

  uint32_t wreg[8];
  int breg[8];
  #pragma unroll
  for (int k = 0; k < 8; k++) {
    int e = base + t + k * 256;
    breg[k] = -1;
    if (e < N_EDGES) {
      float dist = ea[(size_t)e * 6];
      int rel = (dist > 5000.0f) + (dist > 10000.0f);
      int s = ei[e];
      int d = ei[N_EDGES + e];
      wreg[k] = (uint32_t)s | ((uint32_t)rel << 16) | ((uint32_t)(d & 127) << 24);
      breg[k] = d >> 7;
      atomicAdd(&cnt3[d * 3 + rel], 1);
      atomicAdd(&hist[breg[k]], 1);
    }
  }
  __syncthreads();
  for (int i = t; i < NB; i += 256) {
    int h = hist[i];
    hbase[i] = h ? atomicAdd(&bcur[i], h) : 0;
    hist[i] = 0;
  }
  __syncthreads();
  #pragma unroll
  for (int k = 0; k < 8; k++) {
    int b = breg[k];
    if (b >= 0) {
      int r = atomicAdd(&hist[b], 1);
      pairbuf[(size_t)b * BPAD + hbase[b] + r] = wreg[k];
    }
  }
}

// ---------------------------------------------------------------------------
// Parallel scan of node degrees
// ---------------------------------------------------------------------------
__global__ __launch_bounds__(256) void k_scanA(const int* __restrict__ cnt3,
                                               int* __restrict__ excl,
                                               int* __restrict__ bsum) {
  __shared__ int s[256];
  int t = threadIdx.x;
  int n = blockIdx.x * 256 + t;
  int deg = 0;
  if (n < N_NODES) deg = cnt3[3 * n] + cnt3[3 * n + 1] + cnt3[3 * n + 2];
  s[t] = deg;
  __syncthreads();
  for (int ofs = 1; ofs < 256; ofs <<= 1) {
    int v = (t >= ofs) ? s[t - ofs] : 0;
    __syncthreads();
    s[t] += v;
    __syncthreads();
  }
  if (n < N_NODES) excl[n] = s[t] - deg;
  if (t == 255) bsum[blockIdx.x] = s[255];
}

__global__ __launch_bounds__(256) void k_scanB(int* __restrict__ bsum) {
  __shared__ int s[256];
  int t = threadIdx.x;
  int v = (t < NBLK_N) ? bsum[t] : 0;
  s[t] = v;
  __syncthreads();
  for (int ofs = 1; ofs < 256; ofs <<= 1) {
    int u = (t >= ofs) ? s[t - ofs] : 0;
    __syncthreads();
    s[t] += u;
    __syncthreads();
  }
  if (t < NBLK_N) bsum[t] = s[t] - v;   // exclusive
}

__global__ __launch_bounds__(256) void k_scanC(const int* __restrict__ cnt3,
                                               const int* __restrict__ excl,
                                               const int* __restrict__ bsum,
                                               int4* __restrict__ meta,
                                               const float* __restrict__ x,
                                               float4* __restrict__ x4) {
  int n = blockIdx.x * 256 + threadIdx.x;
  if (n >= N_NODES) return;
  meta[n] = make_int4(bsum[blockIdx.x] + excl[n],
                      cnt3[3 * n], cnt3[3 * n + 1], cnt3[3 * n + 2]);
  x4[n] = make_float4(x[n * 3], x[n * 3 + 1], x[n * 3 + 2], 0.0f);
}

// ---------------------------------------------------------------------------
// Pass-2 scatter: one WG per bucket; csr slice written by exactly one WG.
// ---------------------------------------------------------------------------
__global__ __launch_bounds__(256) void k_scat2(const uint32_t* __restrict__ pairbuf,
                                               const int* __restrict__ bcur,
                                               const int4* __restrict__ meta,
                                               uint32_t* __restrict__ csr) {
  __shared__ int lcur[128];
  int b = blockIdx.x;
  int t = threadIdx.x;
  int node0 = b << 7;
  if (t < 128) {
    int n = node0 + t;
    lcur[t] = (n < N_NODES) ? meta[n].x : 0;
  }
  int cnt = bcur[b];
  __syncthreads();
  const uint32_t* pb = pairbuf + (size_t)b * BPAD;
  for (int i = t; i < cnt; i += 256) {
    uint32_t w = pb[i];
    int dl = (int)(w >> 24);
    int p = atomicAdd(&lcur[dl], 1);
    csr[p] = w & 0x00FFFFFFu;   // src | rel<<16
  }
}

// ---------------------------------------------------------------------------
// Layer 0: din=3. Wave per node, lanes parallel over edges, butterfly reduce.
// ---------------------------------------------------------------------------
__global__ __launch_bounds__(256) void k_layer0(const float4* __restrict__ x4,
                                                const float* __restrict__ W0,
                                                const float* __restrict__ root0,
                                                const float* __restrict__ b0,
                                                const int4* __restrict__ meta,
                                                const uint32_t* __restrict__ csr,
                                                float* __restrict__ hout) {
  __shared__ float sW[576], sR[192], sb[64];
  int t = threadIdx.x;
  for (int i = t; i < 576; i += 256) sW[i] = W0[i];
  for (int i = t; i < 192; i += 256) sR[i] = root0[i];
  if (t < 64) sb[t] = b0[t];
  __syncthreads();
  int wid = t >> 6, lane = t & 63;
  int n = blockIdx.x * 4 + wid;
  int4 md = meta[n];
  int off = md.x, c0 = md.y, c1 = md.z, c2 = md.w;
  int cnt = c0 + c1 + c2;
  float a00 = 0, a01 = 0, a02 = 0, a10 = 0, a11 = 0, a12 = 0, a20 = 0, a21 = 0, a22 = 0;
  for (int base = 0; base < cnt; base += 64) {
    int idx = base + lane;
    float4 v = make_float4(0, 0, 0, 0);
    int r = 3;
    if (idx < cnt) {
      uint32_t u = csr[off + idx];
      r = (int)(u >> 16);
      v = x4[u & 0xFFFFu];
    }
    a00 += (r == 0) ? v.x : 0.0f; a01 += (r == 0) ? v.y : 0.0f; a02 += (r == 0) ? v.z : 0.0f;
    a10 += (r == 1) ? v.x : 0.0f; a11 += (r == 1) ? v.y : 0.0f; a12 += (r == 1) ? v.z : 0.0f;
    a20 += (r == 2) ? v.x : 0.0f; a21 += (r == 2) ? v.y : 0.0f; a22 += (r == 2) ? v.z : 0.0f;
  }
  #pragma unroll
  for (int d = 1; d < 64; d <<= 1) {
    a00 += __shfl_xor(a00, d); a01 += __shfl_xor(a01, d); a02 += __shfl_xor(a02, d);
    a10 += __shfl_xor(a10, d); a11 += __shfl_xor(a11, d); a12 += __shfl_xor(a12, d);
    a20 += __shfl_xor(a20, d); a21 += __shfl_xor(a21, d); a22 += __shfl_xor(a22, d);
  }
  float i0 = 1.0f / (float)(c0 > 1 ? c0 : 1);
  float i1 = 1.0f / (float)(c1 > 1 ? c1 : 1);
  float i2 = 1.0f / (float)(c2 > 1 ? c2 : 1);
  float4 xn = x4[n];
  float in[12];
  in[0] = xn.x; in[1] = xn.y; in[2] = xn.z;
  in[3] = a00 * i0; in[4] = a01 * i0; in[5] = a02 * i0;
  in[6] = a10 * i1; in[7] = a11 * i1; in[8] = a12 * i1;
  in[9] = a20 * i2; in[10] = a21 * i2; in[11] = a22 * i2;
  float acc = sb[lane];
  #pragma unroll
  for (int k = 0; k < 3; k++) acc = fmaf(in[k], sR[k * 64 + lane], acc);
  #pragma unroll
  for (int k = 0; k < 9; k++) acc = fmaf(in[3 + k], sW[k * 64 + lane], acc);
  hout[(size_t)n * 64 + lane] = fmaxf(acc, 0.0f);
}

// ---------------------------------------------------------------------------
// Aggregation (layers 1,2): wave per node, lane = feature. Unroll-8 gather MLP.
// ---------------------------------------------------------------------------
#define ACC(E, V) { int r_ = (int)((E) >> 16); \
  a0 += (r_ == 0) ? (V) : 0.0f; a1 += (r_ == 1) ? (V) : 0.0f; a2 += (r_ == 2) ? (V) : 0.0f; }

__global__ __launch_bounds__(256) void k_agg(const float* __restrict__ hin,
                                             const int4* __restrict__ meta,
                                             const uint32_t* __restrict__ csr,
                                             float* __restrict__ mbuf) {
  int t = threadIdx.x, wid = t >> 6, lane = t & 63;
  int n = blockIdx.x * 4 + wid;
  int4 md = meta[n];
  int off = __builtin_amdgcn_readfirstlane(md.x);
  int c0  = __builtin_amdgcn_readfirstlane(md.y);
  int c1  = __builtin_amdgcn_readfirstlane(md.z);
  int c2  = __builtin_amdgcn_readfirstlane(md.w);
  int cnt = c0 + c1 + c2;
  const uint32_t* cp = csr + off;
  float a0 = 0, a1 = 0, a2 = 0;
  int i = 0;
  for (; i + 8 <= cnt; i += 8) {
    uint32_t e0 = cp[i],     e1 = cp[i + 1], e2 = cp[i + 2], e3 = cp[i + 3];
    uint32_t e4 = cp[i + 4], e5 = cp[i + 5], e6 = cp[i + 6], e7 = cp[i + 7];
    float v0 = hin[(int)((e0 & 0xFFFFu) << 6) + lane];
    float v1 = hin[(int)((e1 & 0xFFFFu) << 6) + lane];
    float v2 = hin[(int)((e2 & 0xFFFFu) << 6) + lane];
    float v3 = hin[(int)((e3 & 0xFFFFu) << 6) + lane];
    float v4 = hin[(int)((e4 & 0xFFFFu) << 6) + lane];
    float v5 = hin[(int)((e5 & 0xFFFFu) << 6) + lane];
    float v6 = hin[(int)((e6 & 0xFFFFu) << 6) + lane];
    float v7 = hin[(int)((e7 & 0xFFFFu) << 6) + lane];
    ACC(e0, v0) ACC(e1, v1) ACC(e2, v2) ACC(e3, v3)
    ACC(e4, v4) ACC(e5, v5) ACC(e6, v6) ACC(e7, v7)
  }
  for (; i < cnt; i++) {
    uint32_t e = cp[i];
    float v = hin[(int)((e & 0xFFFFu) << 6) + lane];
    ACC(e, v)
  }
  float* mb = mbuf + (size_t)n * 192;
  mb[lane]       = a0 * (1.0f / (float)(c0 > 1 ? c0 : 1));
  mb[64 + lane]  = a1 * (1.0f / (float)(c1 > 1 ? c1 : 1));
  mb[128 + lane] = a2 * (1.0f / (float)(c2 > 1 ? c2 : 1));
}

// ---------------------------------------------------------------------------
// Transform GEMM: hout[n][j] = relu(b[j] + sum_k A[n][k] * Wcat[k][j])
// ---------------------------------------------------------------------------
__global__ __launch_bounds__(256) void k_gemm(const float* __restrict__ hin,
                                              const float* __restrict__ mbuf,
                                              const float* __restrict__ W,
                                              const float* __restrict__ root,
                                              const float* __restrict__ b,
                                              float* __restrict__ hout) {
  __shared__ float As[64 * 84];
  __shared__ float Bs[64 * 64];
  __shared__ float sb[64];
  int t = threadIdx.x;
  int bn = blockIdx.x * 64;
  if (t < 64) sb[t] = b[t];
  int tn = t & 15, to = t >> 4;
  float acc[4][4] = {};
  for (int kb = 0; kb < 4; kb++) {
    const float4* Bsrc = (const float4*)((kb == 0) ? root : (W + (size_t)(kb - 1) * 4096));
    for (int i2 = t; i2 < 1024; i2 += 256) ((float4*)Bs)[i2] = Bsrc[i2];
    int r = t >> 2;
    int node = bn + r;
    bool ok = node < N_NODES;
    const float* Arow = (kb == 0) ? (hin + (size_t)node * 64)
                                  : (mbuf + (size_t)node * 192 + (size_t)(kb - 1) * 64);
    #pragma unroll
    for (int ii = 0; ii < 4; ii++) {
      int c4 = (t & 3) + 4 * ii;
      float4 v = ok ? ((const float4*)Arow)[c4] : make_float4(0, 0, 0, 0);
      *(float4*)&As[r * 84 + c4 * 4] = v;
    }
    __syncthreads();
    #pragma unroll
    for (int k4 = 0; k4 < 16; k4++) {
      float4 a0 = *(const float4*)&As[(tn)      * 84 + k4 * 4];
      float4 a1 = *(const float4*)&As[(tn + 16) * 84 + k4 * 4];
      float4 a2 = *(const float4*)&As[(tn + 32) * 84 + k4 * 4];
      float4 a3 = *(const float4*)&As[(tn + 48) * 84 + k4 * 4];
      float4 b0 = *(const float4*)&Bs[(k4 * 4 + 0) * 64 + to * 4];
      float4 b1 = *(const float4*)&Bs[(k4 * 4 + 1) * 64 + to * 4];
      float4 b2 = *(const float4*)&Bs[(k4 * 4 + 2) * 64 + to * 4];
      float4 b3 = *(const float4*)&Bs[(k4 * 4 + 3) * 64 + to * 4];
      const float* av[4] = {&a0.x, &a1.x, &a2.x, &a3.x};
      const float* bv[4] = {&b0.x, &b1.x, &b2.x, &b3.x};
      #pragma unroll
      for (int c = 0; c < 4; c++)
        #pragma unroll
        for (int i3 = 0; i3 < 4; i3++)
          #pragma unroll
          for (int j = 0; j < 4; j++)
            acc[i3][j] = fmaf(av[i3][c], bv[c][j], acc[i3][j]);
    }
    __syncthreads();
  }
  #pragma unroll
  for (int i3 = 0; i3 < 4; i3++) {
    int node = bn + tn + 16 * i3;
    if (node < N_NODES) {
      float4 o;
      o.x = fmaxf(acc[i3][0] + sb[to * 4 + 0], 0.0f);
      o.y = fmaxf(acc[i3][1] + sb[to * 4 + 1], 0.0f);
      o.z = fmaxf(acc[i3][2] + sb[to * 4 + 2], 0.0f);
      o.w = fmaxf(acc[i3][3] + sb[to * 4 + 3], 0.0f);
      *(float4*)(hout + (size_t)node * 64 + to * 4) = o;
    }
  }
}

// ---------------------------------------------------------------------------
// Decoder precompute: P[n] = h[n] @ dw1[0:64] + db1 ; Q[n] = h[n] @ dw1[64:128]
// ---------------------------------------------------------------------------
__global__ __launch_bounds__(256) void k_pq(const float* __restrict__ h,
                                            const float* __restrict__ dw1,
                                            const float* __restrict__ db1,
                                            float* __restrict__ P,
                                            float* __restrict__ Q) {
  __shared__ float A[64 * 32], B[64 * 32], sb1[32];
  int t = threadIdx.x;
  {
    const float4* a4 = (const float4*)dw1;
    float4* A4 = (float4*)A;
    float4* B4 = (float4*)B;
    for (int i = t; i < 512; i += 256) A4[i] = a4[i];
    for (int i = t; i < 512; i += 256) B4[i] = a4[512 + i];
    if (t < 32) sb1[t] = db1[t];
  }
  __syncthreads();
  int n = blockIdx.x * 256 + t;
  if (n >= N_NODES) return;
  float p[32], q[32];
  #pragma unroll
  for (int j = 0; j < 32; j++) { p[j] = sb1[j]; q[j] = 0.0f; }
  const float4* h4 = (const float4*)(h + (size_t)n * 64);
  #pragma unroll
  for (int k4 = 0; k4 < 16; k4++) {
    float4 v = h4[k4];
    #pragma unroll
    for (int c = 0; c < 4; c++) {
      float hv = (&v.x)[c];
      int k = k4 * 4 + c;
      #pragma unroll
      for (int j = 0; j < 32; j++) {
        p[j] = fmaf(hv, A[k * 32 + j], p[j]);
        q[j] = fmaf(hv, B[k * 32 + j], q[j]);
      }
    }
  }
  float4* P4 = (float4*)(P + (size_t)n * 32);
  float4* Q4 = (float4*)(Q + (size_t)n * 32);
  #pragma unroll
  for (int j4 = 0; j4 < 8; j4++) {
    P4[j4] = make_float4(p[4 * j4], p[4 * j4 + 1], p[4 * j4 + 2], p[4 * j4 + 3]);
    Q4[j4] = make_float4(q[4 * j4], q[4 * j4 + 1], q[4 * j4 + 2], q[4 * j4 + 3]);
  }
}

// ---------------------------------------------------------------------------
// Decoder edge pass
// ---------------------------------------------------------------------------
__global__ __launch_bounds__(256) void k_dec(const int* __restrict__ ei,
                                             const float* __restrict__ ea,
                                             const float* __restrict__ P,
                                             const float* __restrict__ Q,
                                             const float* __restrict__ dw1,
                                             const float* __restrict__ dw2,
                                             const float* __restrict__ db2,
                                             const float* __restrict__ dw3,
                                             const float* __restrict__ db3,
                                             float* __restrict__ out) {
  __shared__ float C[6 * 32], W2[32 * 16], sb2[16], W3[16];
  __shared__ float sb3;
  int t = threadIdx.x;
  for (int i = t; i < 192; i += 256) C[i] = dw1[128 * 32 + i];
  for (int i = t; i < 512; i += 256) W2[i] = dw2[i];
  if (t < 16) { sb2[t] = db2[t]; W3[t] = dw3[t]; }
  if (t == 0) sb3 = db3[0];
  __syncthreads();
  int e = blockIdx.x * 256 + t;
  int s = ei[e];
  int d = ei[N_EDGES + e];
  float ea6[6];
  #pragma unroll
  for (int i = 0; i < 6; i++) ea6[i] = ea[(size_t)e * 6 + i];
  const float4* Ps = (const float4*)(P + (size_t)s * 32);
  const float4* Qd = (const float4*)(Q + (size_t)d * 32);
  float z1[32];
  #pragma unroll
  for (int j4 = 0; j4 < 8; j4++) {
    float4 pv = Ps[j4];
    float4 qv = Qd[j4];
    #pragma unroll
    for (int c = 0; c < 4; c++) {
      int j = j4 * 4 + c;
      float v = (&pv.x)[c] + (&qv.x)[c];
      #pragma unroll
      for (int k = 0; k < 6; k++) v = fmaf(ea6[k], C[k * 32 + j], v);
      z1[j] = fmaxf(v, 0.0f);
    }
  }
  float o = sb3;
  #pragma unroll
  for (int i = 0; i < 16; i++) {
    float z = sb2[i];
    #pragma unroll
    for (int j = 0; j < 32; j++) z = fmaf(z1[j], W2[j * 16 + i], z);
    o = fmaf(fmaxf(z, 0.0f), W3[i], o);
  }
  out[e] = o;
}

// ---------------------------------------------------------------------------
extern "C" void kernel_launch(void* const* d_in, const int* in_sizes, int n_in,
                              void* d_out, int out_size, void* d_ws, size_t ws_size,
                              hipStream_t stream) {
  const float* x      = (const float*)d_in[0];
  const int*   ei     = (const int*)d_in[1];
  const float* ea     = (const float*)d_in[2];
  const float* w0     = (const float*)d_in[3];
  const float* root0  = (const float*)d_in[4];
  const float* b0     = (const float*)d_in[5];
  const float* w1     = (const float*)d_in[6];
  const float* root1  = (const float*)d_in[7];
  const float* b1     = (const float*)d_in[8];
  const float* w2     = (const float*)d_in[9];
  const float* root2  = (const float*)d_in[10];
  const float* b2     = (const float*)d_in[11];
  const float* dw1    = (const float*)d_in[12];
  const float* db1    = (const float*)d_in[13];
  const float* dw2    = (const float*)d_in[14];
  const float* db2    = (const float*)d_in[15];
  const float* dw3    = (const float*)d_in[16];
  const float* db3    = (const float*)d_in[17];
  float* out = (float*)d_out;

  char* w = (char*)d_ws;
  int* cnt3        = (int*)w;       w += (size_t)N_NODES * 3 * 4;
  int* bcur        = (int*)w;       w += (size_t)NB * 4;          // contiguous after cnt3
  int4* meta       = (int4*)w;      w += (size_t)N_NODES * 16;
  uint32_t* csr    = (uint32_t*)w;  w += (size_t)N_EDGES * 4;
  float4* x4       = (float4*)w;    w += (size_t)N_NODES * 16;
  float* h1        = (float*)w;     w += (size_t)N_NODES * 64 * 4;
  float* h2        = (float*)w;     w += (size_t)N_NODES * 64 * 4;
  float* mbuf      = (float*)w;     w += (size_t)N_NODES * 192 * 4;
  float* P         = mbuf;                      // mbuf dead after layers
  float* Q         = mbuf + (size_t)N_NODES * 32;
  // pairbuf (12.8 MB) aliases h1 + head of h2 (both dead until layer kernels)
  uint32_t* pairbuf = (uint32_t*)h1;
  // excl/bsum alias mbuf (dead until first k_agg)
  int* excl        = (int*)mbuf;
  int* bsum        = (int*)mbuf + N_NODES;

  hipMemsetAsync(cnt3, 0, (size_t)(N_NODES * 3 + NB) * 4, stream);

  k_prep   <<<NWG_PREP, 256, 0, stream>>>(ei, ea, cnt3, bcur, pairbuf);
  k_scanA  <<<NBLK_N, 256, 0, stream>>>(cnt3, excl, bsum);
  k_scanB  <<<1, 256, 0, stream>>>(bsum);
  k_scanC  <<<NBLK_N, 256, 0, stream>>>(cnt3, excl, bsum, meta, x, x4);
  k_scat2  <<<NB, 256, 0, stream>>>(pairbuf, bcur, meta, csr);

  k_layer0 <<<N_NODES / 4, 256, 0, stream>>>(x4, w0, root0, b0, meta, csr, h1);

  k_agg    <<<N_NODES / 4, 256, 0, stream>>>(h1, meta, csr, mbuf);
  k_gemm   <<<(N_NODES + 63) / 64, 256, 0, stream>>>(h1, mbuf, w1, root1, b1, h2);

  k_agg    <<<N_NODES / 4, 256, 0, stream>>>(h2, meta, csr, mbuf);
  k_gemm   <<<(N_NODES + 63) / 64, 256, 0, stream>>>(h2, mbuf, w2, root2, b2, h1);

  k_pq     <<<(N_NODES + 255) / 256, 256, 0, stream>>>(h1, dw1, db1, P, Q);
  k_dec    <<<N_EDGES / 256, 256, 0, stream>>>(ei, ea, P, Q, dw1, dw2, db2, dw3, db3, out);
}

// Round 5
// 508.863 us; speedup vs baseline: 3.2901x; 1.0156x over previous
//
#include <hip/hip_runtime.h>
#include <stdint.h>

#define N_NODES 50000
#define N_EDGES 1600000
#define NBLK_N 196        // ceil(50000/256)
#define NB 391            // buckets of 128 dst nodes
#define BPAD 8192         // padded bucket capacity
#define CHUNK 2048        // edges per prep workgroup
#define NWG_PREP 782      // ceil(1.6M/2048)

__device__ inline float bf2f(uint16_t u) {
  union { uint32_t i; float f; } c; c.i = (uint32_t)u << 16; return c.f;
}
__device__ inline uint16_t f2bf(float f) {
  union { uint32_t i; float f; } c; c.f = f;
  uint32_t b = c.i;
  b += 0x7FFFu + ((b >> 16) & 1u);   // round to nearest even
  return (uint16_t)(b >> 16);
}
__device__ inline float bflo(uint32_t w) {
  union { uint32_t i; float f; } c; c.i = w << 16; return c.f;
}
__device__ inline float bfhi(uint32_t w) {
  union { uint32_t i; float f; } c; c.i = w & 0xFFFF0000u; return c.f;
}

// ---------------------------------------------------------------------------
// Prep + pass-1 binning
// ---------------------------------------------------------------------------
__global__ __launch_bounds__(256) void k_prep(const int* __restrict__ ei,
                                              const float* __restrict__ ea,
                                              int* __restrict__ cnt3,
                                              int* __restrict__ bcur,
                                              uint32_t* __restrict__ pairbuf) {
  __shared__ int hist[NB];
  __shared__ int hbase[NB];
  int t = threadIdx.x;
  int base = blockIdx.x * CHUNK;
  for (int i = t; i < NB; i += 256) hist[i] = 0;
  __syncthreads();

  uint32_t wreg[8];
  int breg[8];
  #pragma unroll
  for (int k = 0; k < 8; k++) {
    int e = base + t + k * 256;
    breg[k] = -1;
    if (e < N_EDGES) {
      float dist = ea[(size_t)e * 6];
      int rel = (dist > 5000.0f) + (dist > 10000.0f);
      int s = ei[e];
      int d = ei[N_EDGES + e];
      wreg[k] = (uint32_t)s | ((uint32_t)rel << 16) | ((uint32_t)(d & 127) << 24);
      breg[k] = d >> 7;
      atomicAdd(&cnt3[d * 3 + rel], 1);
      atomicAdd(&hist[breg[k]], 1);
    }
  }
  __syncthreads();
  for (int i = t; i < NB; i += 256) {
    int h = hist[i];
    hbase[i] = h ? atomicAdd(&bcur[i], h) : 0;
    hist[i] = 0;
  }
  __syncthreads();
  #pragma unroll
  for (int k = 0; k < 8; k++) {
    int b = breg[k];
    if (b >= 0) {
      int r = atomicAdd(&hist[b], 1);
      pairbuf[(size_t)b * BPAD + hbase[b] + r] = wreg[k];
    }
  }
}

// ---------------------------------------------------------------------------
// Parallel scan of node degrees
// ---------------------------------------------------------------------------
__global__ __launch_bounds__(256) void k_scanA(const int* __restrict__ cnt3,
                                               int* __restrict__ excl,
                                               int* __restrict__ bsum) {
  __shared__ int s[256];
  int t = threadIdx.x;
  int n = blockIdx.x * 256 + t;
  int deg = 0;
  if (n < N_NODES) deg = cnt3[3 * n] + cnt3[3 * n + 1] + cnt3[3 * n + 2];
  s[t] = deg;
  __syncthreads();
  for (int ofs = 1; ofs < 256; ofs <<= 1) {
    int v = (t >= ofs) ? s[t - ofs] : 0;
    __syncthreads();
    s[t] += v;
    __syncthreads();
  }
  if (n < N_NODES) excl[n] = s[t] - deg;
  if (t == 255) bsum[blockIdx.x] = s[255];
}

__global__ __launch_bounds__(256) void k_scanB(int* __restrict__ bsum) {
  __shared__ int s[256];
  int t = threadIdx.x;
  int v = (t < NBLK_N) ? bsum[t] : 0;
  s[t] = v;
  __syncthreads();
  for (int ofs = 1; ofs < 256; ofs <<= 1) {
    int u = (t >= ofs) ? s[t - ofs] : 0;
    __syncthreads();
    s[t] += u;
    __syncthreads();
  }
  if (t < NBLK_N) bsum[t] = s[t] - v;   // exclusive
}

__global__ __launch_bounds__(256) void k_scanC(const int* __restrict__ cnt3,
                                               const int* __restrict__ excl,
                                               const int* __restrict__ bsum,
                                               int4* __restrict__ meta,
                                               const float* __restrict__ x,
                                               float4* __restrict__ x4) {
  int n = blockIdx.x * 256 + threadIdx.x;
  if (n >= N_NODES) return;
  meta[n] = make_int4(bsum[blockIdx.x] + excl[n],
                      cnt3[3 * n], cnt3[3 * n + 1], cnt3[3 * n + 2]);
  x4[n] = make_float4(x[n * 3], x[n * 3 + 1], x[n * 3 + 2], 0.0f);
}

// ---------------------------------------------------------------------------
// Pass-2 scatter
// ---------------------------------------------------------------------------
__global__ __launch_bounds__(256) void k_scat2(const uint32_t* __restrict__ pairbuf,
                                               const int* __restrict__ bcur,
                                               const int4* __restrict__ meta,
                                               uint32_t* __restrict__ csr) {
  __shared__ int lcur[128];
  int b = blockIdx.x;
  int t = threadIdx.x;
  int node0 = b << 7;
  if (t < 128) {
    int n = node0 + t;
    lcur[t] = (n < N_NODES) ? meta[n].x : 0;
  }
  int cnt = bcur[b];
  __syncthreads();
  const uint32_t* pb = pairbuf + (size_t)b * BPAD;
  for (int i = t; i < cnt; i += 256) {
    uint32_t w = pb[i];
    int dl = (int)(w >> 24);
    int p = atomicAdd(&lcur[dl], 1);
    csr[p] = w & 0x00FFFFFFu;   // src | rel<<16
  }
}

// ---------------------------------------------------------------------------
// Layer 0: din=3. Wave per node; writes f32 h + bf16 shadow.
// ---------------------------------------------------------------------------
__global__ __launch_bounds__(256) void k_layer0(const float4* __restrict__ x4,
                                                const float* __restrict__ W0,
                                                const float* __restrict__ root0,
                                                const float* __restrict__ b0,
                                                const int4* __restrict__ meta,
                                                const uint32_t* __restrict__ csr,
                                                float* __restrict__ hout,
                                                uint16_t* __restrict__ hbf) {
  __shared__ float sW[576], sR[192], sb[64];
  int t = threadIdx.x;
  for (int i = t; i < 576; i += 256) sW[i] = W0[i];
  for (int i = t; i < 192; i += 256) sR[i] = root0[i];
  if (t < 64) sb[t] = b0[t];
  __syncthreads();
  int wid = t >> 6, lane = t & 63;
  int n = blockIdx.x * 4 + wid;
  int4 md = meta[n];
  int off = md.x, c0 = md.y, c1 = md.z, c2 = md.w;
  int cnt = c0 + c1 + c2;
  float a00 = 0, a01 = 0, a02 = 0, a10 = 0, a11 = 0, a12 = 0, a20 = 0, a21 = 0, a22 = 0;
  for (int base = 0; base < cnt; base += 64) {
    int idx = base + lane;
    float4 v = make_float4(0, 0, 0, 0);
    int r = 3;
    if (idx < cnt) {
      uint32_t u = csr[off + idx];
      r = (int)(u >> 16);
      v = x4[u & 0xFFFFu];
    }
    a00 += (r == 0) ? v.x : 0.0f; a01 += (r == 0) ? v.y : 0.0f; a02 += (r == 0) ? v.z : 0.0f;
    a10 += (r == 1) ? v.x : 0.0f; a11 += (r == 1) ? v.y : 0.0f; a12 += (r == 1) ? v.z : 0.0f;
    a20 += (r == 2) ? v.x : 0.0f; a21 += (r == 2) ? v.y : 0.0f; a22 += (r == 2) ? v.z : 0.0f;
  }
  #pragma unroll
  for (int d = 1; d < 64; d <<= 1) {
    a00 += __shfl_xor(a00, d); a01 += __shfl_xor(a01, d); a02 += __shfl_xor(a02, d);
    a10 += __shfl_xor(a10, d); a11 += __shfl_xor(a11, d); a12 += __shfl_xor(a12, d);
    a20 += __shfl_xor(a20, d); a21 += __shfl_xor(a21, d); a22 += __shfl_xor(a22, d);
  }
  float i0 = 1.0f / (float)(c0 > 1 ? c0 : 1);
  float i1 = 1.0f / (float)(c1 > 1 ? c1 : 1);
  float i2 = 1.0f / (float)(c2 > 1 ? c2 : 1);
  float4 xn = x4[n];
  float in[12];
  in[0] = xn.x; in[1] = xn.y; in[2] = xn.z;
  in[3] = a00 * i0; in[4] = a01 * i0; in[5] = a02 * i0;
  in[6] = a10 * i1; in[7] = a11 * i1; in[8] = a12 * i1;
  in[9] = a20 * i2; in[10] = a21 * i2; in[11] = a22 * i2;
  float acc = sb[lane];
  #pragma unroll
  for (int k = 0; k < 3; k++) acc = fmaf(in[k], sR[k * 64 + lane], acc);
  #pragma unroll
  for (int k = 0; k < 9; k++) acc = fmaf(in[3 + k], sW[k * 64 + lane], acc);
  float h = fmaxf(acc, 0.0f);
  hout[(size_t)n * 64 + lane] = h;
  hbf[(size_t)n * 64 + lane] = f2bf(h);
}

// ---------------------------------------------------------------------------
// Aggregation: wave per node, lane = feature, bf16 gathers (128 B/edge).
// ---------------------------------------------------------------------------
#define ACC(E, V) { int r_ = (int)((E) >> 16); \
  a0 += (r_ == 0) ? (V) : 0.0f; a1 += (r_ == 1) ? (V) : 0.0f; a2 += (r_ == 2) ? (V) : 0.0f; }

__global__ __launch_bounds__(256) void k_agg(const uint16_t* __restrict__ hbf,
                                             const int4* __restrict__ meta,
                                             const uint32_t* __restrict__ csr,
                                             float* __restrict__ mbuf) {
  int t = threadIdx.x, wid = t >> 6, lane = t & 63;
  int n = blockIdx.x * 4 + wid;
  int4 md = meta[n];
  int off = __builtin_amdgcn_readfirstlane(md.x);
  int c0  = __builtin_amdgcn_readfirstlane(md.y);
  int c1  = __builtin_amdgcn_readfirstlane(md.z);
  int c2  = __builtin_amdgcn_readfirstlane(md.w);
  int cnt = c0 + c1 + c2;
  const uint32_t* cp = csr + off;
  float a0 = 0, a1 = 0, a2 = 0;
  int i = 0;
  for (; i + 8 <= cnt; i += 8) {
    uint32_t e0 = cp[i],     e1 = cp[i + 1], e2 = cp[i + 2], e3 = cp[i + 3];
    uint32_t e4 = cp[i + 4], e5 = cp[i + 5], e6 = cp[i + 6], e7 = cp[i + 7];
    float v0 = bf2f(hbf[(int)((e0 & 0xFFFFu) << 6) + lane]);
    float v1 = bf2f(hbf[(int)((e1 & 0xFFFFu) << 6) + lane]);
    float v2 = bf2f(hbf[(int)((e2 & 0xFFFFu) << 6) + lane]);
    float v3 = bf2f(hbf[(int)((e3 & 0xFFFFu) << 6) + lane]);
    float v4 = bf2f(hbf[(int)((e4 & 0xFFFFu) << 6) + lane]);
    float v5 = bf2f(hbf[(int)((e5 & 0xFFFFu) << 6) + lane]);
    float v6 = bf2f(hbf[(int)((e6 & 0xFFFFu) << 6) + lane]);
    float v7 = bf2f(hbf[(int)((e7 & 0xFFFFu) << 6) + lane]);
    ACC(e0, v0) ACC(e1, v1) ACC(e2, v2) ACC(e3, v3)
    ACC(e4, v4) ACC(e5, v5) ACC(e6, v6) ACC(e7, v7)
  }
  for (; i < cnt; i++) {
    uint32_t e = cp[i];
    float v = bf2f(hbf[(int)((e & 0xFFFFu) << 6) + lane]);
    ACC(e, v)
  }
  float* mb = mbuf + (size_t)n * 192;
  mb[lane]       = a0 * (1.0f / (float)(c0 > 1 ? c0 : 1));
  mb[64 + lane]  = a1 * (1.0f / (float)(c1 > 1 ? c1 : 1));
  mb[128 + lane] = a2 * (1.0f / (float)(c2 > 1 ? c2 : 1));
}

// ---------------------------------------------------------------------------
// Transform GEMM: f32; epilogue also writes bf16 shadow (if hbf != null)
// ---------------------------------------------------------------------------
__global__ __launch_bounds__(256) void k_gemm(const float* __restrict__ hin,
                                              const float* __restrict__ mbuf,
                                              const float* __restrict__ W,
                                              const float* __restrict__ root,
                                              const float* __restrict__ b,
                                              float* __restrict__ hout,
                                              uint16_t* __restrict__ hbf) {
  __shared__ float As[64 * 84];
  __shared__ float Bs[64 * 64];
  __shared__ float sb[64];
  int t = threadIdx.x;
  int bn = blockIdx.x * 64;
  if (t < 64) sb[t] = b[t];
  int tn = t & 15, to = t >> 4;
  float acc[4][4] = {};
  for (int kb = 0; kb < 4; kb++) {
    const float4* Bsrc = (const float4*)((kb == 0) ? root : (W + (size_t)(kb - 1) * 4096));
    for (int i2 = t; i2 < 1024; i2 += 256) ((float4*)Bs)[i2] = Bsrc[i2];
    int r = t >> 2;
    int node = bn + r;
    bool ok = node < N_NODES;
    const float* Arow = (kb == 0) ? (hin + (size_t)node * 64)
                                  : (mbuf + (size_t)node * 192 + (size_t)(kb - 1) * 64);
    #pragma unroll
    for (int ii = 0; ii < 4; ii++) {
      int c4 = (t & 3) + 4 * ii;
      float4 v = ok ? ((const float4*)Arow)[c4] : make_float4(0, 0, 0, 0);
      *(float4*)&As[r * 84 + c4 * 4] = v;
    }
    __syncthreads();
    #pragma unroll
    for (int k4 = 0; k4 < 16; k4++) {
      float4 a0 = *(const float4*)&As[(tn)      * 84 + k4 * 4];
      float4 a1 = *(const float4*)&As[(tn + 16) * 84 + k4 * 4];
      float4 a2 = *(const float4*)&As[(tn + 32) * 84 + k4 * 4];
      float4 a3 = *(const float4*)&As[(tn + 48) * 84 + k4 * 4];
      float4 b0 = *(const float4*)&Bs[(k4 * 4 + 0) * 64 + to * 4];
      float4 b1 = *(const float4*)&Bs[(k4 * 4 + 1) * 64 + to * 4];
      float4 b2 = *(const float4*)&Bs[(k4 * 4 + 2) * 64 + to * 4];
      float4 b3 = *(const float4*)&Bs[(k4 * 4 + 3) * 64 + to * 4];
      const float* av[4] = {&a0.x, &a1.x, &a2.x, &a3.x};
      const float* bv[4] = {&b0.x, &b1.x, &b2.x, &b3.x};
      #pragma unroll
      for (int c = 0; c < 4; c++)
        #pragma unroll
        for (int i3 = 0; i3 < 4; i3++)
          #pragma unroll
          for (int j = 0; j < 4; j++)
            acc[i3][j] = fmaf(av[i3][c], bv[c][j], acc[i3][j]);
    }
    __syncthreads();
  }
  #pragma unroll
  for (int i3 = 0; i3 < 4; i3++) {
    int node = bn + tn + 16 * i3;
    if (node < N_NODES) {
      float4 o;
      o.x = fmaxf(acc[i3][0] + sb[to * 4 + 0], 0.0f);
      o.y = fmaxf(acc[i3][1] + sb[to * 4 + 1], 0.0f);
      o.z = fmaxf(acc[i3][2] + sb[to * 4 + 2], 0.0f);
      o.w = fmaxf(acc[i3][3] + sb[to * 4 + 3], 0.0f);
      *(float4*)(hout + (size_t)node * 64 + to * 4) = o;
      if (hbf) {
        uint2 pk;
        pk.x = (uint32_t)f2bf(o.x) | ((uint32_t)f2bf(o.y) << 16);
        pk.y = (uint32_t)f2bf(o.z) | ((uint32_t)f2bf(o.w) << 16);
        *(uint2*)(hbf + (size_t)node * 64 + to * 4) = pk;
      }
    }
  }
}

// ---------------------------------------------------------------------------
// Decoder precompute: P,Q stored as bf16 (64 B rows)
// ---------------------------------------------------------------------------
__global__ __launch_bounds__(256) void k_pq(const float* __restrict__ h,
                                            const float* __restrict__ dw1,
                                            const float* __restrict__ db1,
                                            uint16_t* __restrict__ Pb,
                                            uint16_t* __restrict__ Qb) {
  __shared__ float A[64 * 32], B[64 * 32], sb1[32];
  int t = threadIdx.x;
  {
    const float4* a4 = (const float4*)dw1;
    float4* A4 = (float4*)A;
    float4* B4 = (float4*)B;
    for (int i = t; i < 512; i += 256) A4[i] = a4[i];
    for (int i = t; i < 512; i += 256) B4[i] = a4[512 + i];
    if (t < 32) sb1[t] = db1[t];
  }
  __syncthreads();
  int n = blockIdx.x * 256 + t;
  if (n >= N_NODES) return;
  float p[32], q[32];
  #pragma unroll
  for (int j = 0; j < 32; j++) { p[j] = sb1[j]; q[j] = 0.0f; }
  const float4* h4 = (const float4*)(h + (size_t)n * 64);
  #pragma unroll
  for (int k4 = 0; k4 < 16; k4++) {
    float4 v = h4[k4];
    #pragma unroll
    for (int c = 0; c < 4; c++) {
      float hv = (&v.x)[c];
      int k = k4 * 4 + c;
      #pragma unroll
      for (int j = 0; j < 32; j++) {
        p[j] = fmaf(hv, A[k * 32 + j], p[j]);
        q[j] = fmaf(hv, B[k * 32 + j], q[j]);
      }
    }
  }
  uint32_t pw[16], qw[16];
  #pragma unroll
  for (int j = 0; j < 16; j++) {
    pw[j] = (uint32_t)f2bf(p[2 * j]) | ((uint32_t)f2bf(p[2 * j + 1]) << 16);
    qw[j] = (uint32_t)f2bf(q[2 * j]) | ((uint32_t)f2bf(q[2 * j + 1]) << 16);
  }
  uint4* P4 = (uint4*)(Pb + (size_t)n * 32);
  uint4* Q4 = (uint4*)(Qb + (size_t)n * 32);
  #pragma unroll
  for (int j4 = 0; j4 < 4; j4++) {
    P4[j4] = make_uint4(pw[4 * j4], pw[4 * j4 + 1], pw[4 * j4 + 2], pw[4 * j4 + 3]);
    Q4[j4] = make_uint4(qw[4 * j4], qw[4 * j4 + 1], qw[4 * j4 + 2], qw[4 * j4 + 3]);
  }
}

// ---------------------------------------------------------------------------
// Decoder edge pass: bf16 P/Q gathers (one 64 B line per row)
// ---------------------------------------------------------------------------
__global__ __launch_bounds__(256) void k_dec(const int* __restrict__ ei,
                                             const float* __restrict__ ea,
                                             const uint16_t* __restrict__ Pb,
                                             const uint16_t* __restrict__ Qb,
                                             const float* __restrict__ dw1,
                                             const float* __restrict__ dw2,
                                             const float* __restrict__ db2,
                                             const float* __restrict__ dw3,
                                             const float* __restrict__ db3,
                                             float* __restrict__ out) {
  __shared__ float C[6 * 32], W2[32 * 16], sb2[16], W3[16];
  __shared__ float sb3;
  int t = threadIdx.x;
  for (int i = t; i < 192; i += 256) C[i] = dw1[128 * 32 + i];
  for (int i = t; i < 512; i += 256) W2[i] = dw2[i];
  if (t < 16) { sb2[t] = db2[t]; W3[t] = dw3[t]; }
  if (t == 0) sb3 = db3[0];
  __syncthreads();
  int e = blockIdx.x * 256 + t;
  int s = ei[e];
  int d = ei[N_EDGES + e];
  float ea6[6];
  #pragma unroll
  for (int i = 0; i < 6; i++) ea6[i] = ea[(size_t)e * 6 + i];
  const uint4* Ps = (const uint4*)(Pb + (size_t)s * 32);
  const uint4* Qd = (const uint4*)(Qb + (size_t)d * 32);
  float z1[32];
  #pragma unroll
  for (int j4 = 0; j4 < 4; j4++) {
    uint4 pv = Ps[j4];
    uint4 qv = Qd[j4];
    const uint32_t* pw = &pv.x;
    const uint32_t* qw = &qv.x;
    #pragma unroll
    for (int c = 0; c < 4; c++) {
      int j = j4 * 8 + c * 2;
      float vlo = bflo(pw[c]) + bflo(qw[c]);
      float vhi = bfhi(pw[c]) + bfhi(qw[c]);
      #pragma unroll
      for (int k = 0; k < 6; k++) {
        vlo = fmaf(ea6[k], C[k * 32 + j], vlo);
        vhi = fmaf(ea6[k], C[k * 32 + j + 1], vhi);
      }
      z1[j]     = fmaxf(vlo, 0.0f);
      z1[j + 1] = fmaxf(vhi, 0.0f);
    }
  }
  float o = sb3;
  #pragma unroll
  for (int i = 0; i < 16; i++) {
    float z = sb2[i];
    #pragma unroll
    for (int j = 0; j < 32; j++) z = fmaf(z1[j], W2[j * 16 + i], z);
    o = fmaf(fmaxf(z, 0.0f), W3[i], o);
  }
  out[e] = o;
}

// ---------------------------------------------------------------------------
extern "C" void kernel_launch(void* const* d_in, const int* in_sizes, int n_in,
                              void* d_out, int out_size, void* d_ws, size_t ws_size,
                              hipStream_t stream) {
  const float* x      = (const float*)d_in[0];
  const int*   ei     = (const int*)d_in[1];
  const float* ea     = (const float*)d_in[2];
  const float* w0     = (const float*)d_in[3];
  const float* root0  = (const float*)d_in[4];
  const float* b0     = (const float*)d_in[5];
  const float* w1     = (const float*)d_in[6];
  const float* root1  = (const float*)d_in[7];
  const float* b1     = (const float*)d_in[8];
  const float* w2     = (const float*)d_in[9];
  const float* root2  = (const float*)d_in[10];
  const float* b2     = (const float*)d_in[11];
  const float* dw1    = (const float*)d_in[12];
  const float* db1    = (const float*)d_in[13];
  const float* dw2    = (const float*)d_in[14];
  const float* db2    = (const float*)d_in[15];
  const float* dw3    = (const float*)d_in[16];
  const float* db3    = (const float*)d_in[17];
  float* out = (float*)d_out;

  char* w = (char*)d_ws;
  int* cnt3        = (int*)w;       w += (size_t)N_NODES * 3 * 4;
  int* bcur        = (int*)w;       w += (size_t)NB * 4;
  int4* meta       = (int4*)w;      w += (size_t)N_NODES * 16;
  uint32_t* csr    = (uint32_t*)w;  w += (size_t)N_EDGES * 4;
  float4* x4       = (float4*)w;    w += (size_t)N_NODES * 16;
  float* h1        = (float*)w;     w += (size_t)N_NODES * 64 * 4;
  float* h2        = (float*)w;     w += (size_t)N_NODES * 64 * 4;
  float* mbuf      = (float*)w;     w += (size_t)N_NODES * 192 * 4;
  uint16_t* hbf1   = (uint16_t*)w;  w += (size_t)N_NODES * 64 * 2;
  uint16_t* hbf2   = (uint16_t*)w;  w += (size_t)N_NODES * 64 * 2;
  // Pb/Qb alias mbuf (dead after second k_gemm)
  uint16_t* Pb     = (uint16_t*)mbuf;
  uint16_t* Qb     = Pb + (size_t)N_NODES * 32;
  // pairbuf (12.81 MB) aliases h1 + head of h2 (dead until layer kernels)
  uint32_t* pairbuf = (uint32_t*)h1;
  // excl/bsum alias mbuf (dead until first k_agg)
  int* excl        = (int*)mbuf;
  int* bsum        = (int*)mbuf + N_NODES;

  hipMemsetAsync(cnt3, 0, (size_t)(N_NODES * 3 + NB) * 4, stream);

  k_prep   <<<NWG_PREP, 256, 0, stream>>>(ei, ea, cnt3, bcur, pairbuf);
  k_scanA  <<<NBLK_N, 256, 0, stream>>>(cnt3, excl, bsum);
  k_scanB  <<<1, 256, 0, stream>>>(bsum);
  k_scanC  <<<NBLK_N, 256, 0, stream>>>(cnt3, excl, bsum, meta, x, x4);
  k_scat2  <<<NB, 256, 0, stream>>>(pairbuf, bcur, meta, csr);

  k_layer0 <<<N_NODES / 4, 256, 0, stream>>>(x4, w0, root0, b0, meta, csr, h1, hbf1);

  k_agg    <<<N_NODES / 4, 256, 0, stream>>>(hbf1, meta, csr, mbuf);
  k_gemm   <<<(N_NODES + 63) / 64, 256, 0, stream>>>(h1, mbuf, w1, root1, b1, h2, hbf2);

  k_agg    <<<N_NODES / 4, 256, 0, stream>>>(hbf2, meta, csr, mbuf);
  k_gemm   <<<(N_NODES + 63) / 64, 256, 0, stream>>>(h2, mbuf, w2, root2, b2, h1, (uint16_t*)nullptr);

  k_pq     <<<(N_NODES + 255) / 256, 256, 0, stream>>>(h1, dw1, db1, Pb, Qb);
  k_dec    <<<N_EDGES / 256, 256, 0, stream>>>(ei, ea, Pb, Qb, dw1, dw2, db2, dw3, db3, out);
}

// Round 6
// 451.059 us; speedup vs baseline: 3.7117x; 1.1282x over previous
//
#include <hip/hip_runtime.h>
#include <stdint.h>

#define N_NODES 50000
#define N_EDGES 1600000
#define NBLK_N 196        // ceil(50000/256)
#define NB 391            // buckets of 128 dst nodes
#define BPAD 8192         // padded bucket capacity
#define CHUNK 2048        // edges per prep workgroup
#define NWG_PREP 782      // ceil(1.6M/2048)

__device__ inline float bf2f(uint16_t u) {
  union { uint32_t i; float f; } c; c.i = (uint32_t)u << 16; return c.f;
}
__device__ inline uint16_t f2bf(float f) {
  union { uint32_t i; float f; } c; c.f = f;
  uint32_t b = c.i;
  b += 0x7FFFu + ((b >> 16) & 1u);   // round to nearest even
  return (uint16_t)(b >> 16);
}
__device__ inline float bflo(uint32_t w) {
  union { uint32_t i; float f; } c; c.i = w << 16; return c.f;
}
__device__ inline float bfhi(uint32_t w) {
  union { uint32_t i; float f; } c; c.i = w & 0xFFFF0000u; return c.f;
}

// ---------------------------------------------------------------------------
// Prep + pass-1 binning
// ---------------------------------------------------------------------------
__global__ __launch_bounds__(256) void k_prep(const int* __restrict__ ei,
                                              const float* __restrict__ ea,
                                              int* __restrict__ cnt3,
                                              int* __restrict__ bcur,
                                              uint32_t* __restrict__ pairbuf) {
  __shared__ int hist[NB];
  __shared__ int hbase[NB];
  int t = threadIdx.x;
  int base = blockIdx.x * CHUNK;
  for (int i = t; i < NB; i += 256) hist[i] = 0;
  __syncthreads();

  uint32_t wreg[8];
  int breg[8];
  #pragma unroll
  for (int k = 0; k < 8; k++) {
    int e = base + t + k * 256;
    breg[k] = -1;
    if (e < N_EDGES) {
      float dist = ea[(size_t)e * 6];
      int rel = (dist > 5000.0f) + (dist > 10000.0f);
      int s = ei[e];
      int d = ei[N_EDGES + e];
      wreg[k] = (uint32_t)s | ((uint32_t)rel << 16) | ((uint32_t)(d & 127) << 24);
      breg[k] = d >> 7;
      atomicAdd(&cnt3[d * 3 + rel], 1);
      atomicAdd(&hist[breg[k]], 1);
    }
  }
  __syncthreads();
  for (int i = t; i < NB; i += 256) {
    int h = hist[i];
    hbase[i] = h ? atomicAdd(&bcur[i], h) : 0;
    hist[i] = 0;
  }
  __syncthreads();
  #pragma unroll
  for (int k = 0; k < 8; k++) {
    int b = breg[k];
    if (b >= 0) {
      int r = atomicAdd(&hist[b], 1);
      pairbuf[(size_t)b * BPAD + hbase[b] + r] = wreg[k];
    }
  }
}

// ---------------------------------------------------------------------------
// Parallel scan of node degrees
// ---------------------------------------------------------------------------
__global__ __launch_bounds__(256) void k_scanA(const int* __restrict__ cnt3,
                                               int* __restrict__ excl,
                                               int* __restrict__ bsum) {
  __shared__ int s[256];
  int t = threadIdx.x;
  int n = blockIdx.x * 256 + t;
  int deg = 0;
  if (n < N_NODES) deg = cnt3[3 * n] + cnt3[3 * n + 1] + cnt3[3 * n + 2];
  s[t] = deg;
  __syncthreads();
  for (int ofs = 1; ofs < 256; ofs <<= 1) {
    int v = (t >= ofs) ? s[t - ofs] : 0;
    __syncthreads();
    s[t] += v;
    __syncthreads();
  }
  if (n < N_NODES) excl[n] = s[t] - deg;
  if (t == 255) bsum[blockIdx.x] = s[255];
}

__global__ __launch_bounds__(256) void k_scanB(int* __restrict__ bsum) {
  __shared__ int s[256];
  int t = threadIdx.x;
  int v = (t < NBLK_N) ? bsum[t] : 0;
  s[t] = v;
  __syncthreads();
  for (int ofs = 1; ofs < 256; ofs <<= 1) {
    int u = (t >= ofs) ? s[t - ofs] : 0;
    __syncthreads();
    s[t] += u;
    __syncthreads();
  }
  if (t < NBLK_N) bsum[t] = s[t] - v;   // exclusive
}

__global__ __launch_bounds__(256) void k_scanC(const int* __restrict__ cnt3,
                                               const int* __restrict__ excl,
                                               const int* __restrict__ bsum,
                                               int4* __restrict__ meta,
                                               const float* __restrict__ x,
                                               float4* __restrict__ x4) {
  int n = blockIdx.x * 256 + threadIdx.x;
  if (n >= N_NODES) return;
  meta[n] = make_int4(bsum[blockIdx.x] + excl[n],
                      cnt3[3 * n], cnt3[3 * n + 1], cnt3[3 * n + 2]);
  x4[n] = make_float4(x[n * 3], x[n * 3 + 1], x[n * 3 + 2], 0.0f);
}

// ---------------------------------------------------------------------------
// Pass-2 scatter
// ---------------------------------------------------------------------------
__global__ __launch_bounds__(256) void k_scat2(const uint32_t* __restrict__ pairbuf,
                                               const int* __restrict__ bcur,
                                               const int4* __restrict__ meta,
                                               uint32_t* __restrict__ csr) {
  __shared__ int lcur[128];
  int b = blockIdx.x;
  int t = threadIdx.x;
  int node0 = b << 7;
  if (t < 128) {
    int n = node0 + t;
    lcur[t] = (n < N_NODES) ? meta[n].x : 0;
  }
  int cnt = bcur[b];
  __syncthreads();
  const uint32_t* pb = pairbuf + (size_t)b * BPAD;
  for (int i = t; i < cnt; i += 256) {
    uint32_t w = pb[i];
    int dl = (int)(w >> 24);
    int p = atomicAdd(&lcur[dl], 1);
    csr[p] = w & 0x00FFFFFFu;   // src | rel<<16
  }
}

// ---------------------------------------------------------------------------
// Layer 0: din=3. Wave per node; writes f32 h + bf16 shadow.
// ---------------------------------------------------------------------------
__global__ __launch_bounds__(256) void k_layer0(const float4* __restrict__ x4,
                                                const float* __restrict__ W0,
                                                const float* __restrict__ root0,
                                                const float* __restrict__ b0,
                                                const int4* __restrict__ meta,
                                                const uint32_t* __restrict__ csr,
                                                float* __restrict__ hout,
                                                uint16_t* __restrict__ hbf) {
  __shared__ float sW[576], sR[192], sb[64];
  int t = threadIdx.x;
  for (int i = t; i < 576; i += 256) sW[i] = W0[i];
  for (int i = t; i < 192; i += 256) sR[i] = root0[i];
  if (t < 64) sb[t] = b0[t];
  __syncthreads();
  int wid = t >> 6, lane = t & 63;
  int n = blockIdx.x * 4 + wid;
  int4 md = meta[n];
  int off = md.x, c0 = md.y, c1 = md.z, c2 = md.w;
  int cnt = c0 + c1 + c2;
  float a00 = 0, a01 = 0, a02 = 0, a10 = 0, a11 = 0, a12 = 0, a20 = 0, a21 = 0, a22 = 0;
  for (int base = 0; base < cnt; base += 64) {
    int idx = base + lane;
    float4 v = make_float4(0, 0, 0, 0);
    int r = 3;
    if (idx < cnt) {
      uint32_t u = csr[off + idx];
      r = (int)(u >> 16);
      v = x4[u & 0xFFFFu];
    }
    a00 += (r == 0) ? v.x : 0.0f; a01 += (r == 0) ? v.y : 0.0f; a02 += (r == 0) ? v.z : 0.0f;
    a10 += (r == 1) ? v.x : 0.0f; a11 += (r == 1) ? v.y : 0.0f; a12 += (r == 1) ? v.z : 0.0f;
    a20 += (r == 2) ? v.x : 0.0f; a21 += (r == 2) ? v.y : 0.0f; a22 += (r == 2) ? v.z : 0.0f;
  }
  #pragma unroll
  for (int d = 1; d < 64; d <<= 1) {
    a00 += __shfl_xor(a00, d); a01 += __shfl_xor(a01, d); a02 += __shfl_xor(a02, d);
    a10 += __shfl_xor(a10, d); a11 += __shfl_xor(a11, d); a12 += __shfl_xor(a12, d);
    a20 += __shfl_xor(a20, d); a21 += __shfl_xor(a21, d); a22 += __shfl_xor(a22, d);
  }
  float i0 = 1.0f / (float)(c0 > 1 ? c0 : 1);
  float i1 = 1.0f / (float)(c1 > 1 ? c1 : 1);
  float i2 = 1.0f / (float)(c2 > 1 ? c2 : 1);
  float4 xn = x4[n];
  float in[12];
  in[0] = xn.x; in[1] = xn.y; in[2] = xn.z;
  in[3] = a00 * i0; in[4] = a01 * i0; in[5] = a02 * i0;
  in[6] = a10 * i1; in[7] = a11 * i1; in[8] = a12 * i1;
  in[9] = a20 * i2; in[10] = a21 * i2; in[11] = a22 * i2;
  float acc = sb[lane];
  #pragma unroll
  for (int k = 0; k < 3; k++) acc = fmaf(in[k], sR[k * 64 + lane], acc);
  #pragma unroll
  for (int k = 0; k < 9; k++) acc = fmaf(in[3 + k], sW[k * 64 + lane], acc);
  float h = fmaxf(acc, 0.0f);
  hout[(size_t)n * 64 + lane] = h;
  hbf[(size_t)n * 64 + lane] = f2bf(h);
}

// ---------------------------------------------------------------------------
// Aggregation: wave per node, lane = feature, bf16 gathers (128 B/edge).
// ---------------------------------------------------------------------------
#define ACC(E, V) { int r_ = (int)((E) >> 16); \
  a0 += (r_ == 0) ? (V) : 0.0f; a1 += (r_ == 1) ? (V) : 0.0f; a2 += (r_ == 2) ? (V) : 0.0f; }

__global__ __launch_bounds__(256) void k_agg(const uint16_t* __restrict__ hbf,
                                             const int4* __restrict__ meta,
                                             const uint32_t* __restrict__ csr,
                                             float* __restrict__ mbuf) {
  int t = threadIdx.x, wid = t >> 6, lane = t & 63;
  int n = blockIdx.x * 4 + wid;
  int4 md = meta[n];
  int off = __builtin_amdgcn_readfirstlane(md.x);
  int c0  = __builtin_amdgcn_readfirstlane(md.y);
  int c1  = __builtin_amdgcn_readfirstlane(md.z);
  int c2  = __builtin_amdgcn_readfirstlane(md.w);
  int cnt = c0 + c1 + c2;
  const uint32_t* cp = csr + off;
  float a0 = 0, a1 = 0, a2 = 0;
  int i = 0;
  for (; i + 8 <= cnt; i += 8) {
    uint32_t e0 = cp[i],     e1 = cp[i + 1], e2 = cp[i + 2], e3 = cp[i + 3];
    uint32_t e4 = cp[i + 4], e5 = cp[i + 5], e6 = cp[i + 6], e7 = cp[i + 7];
    float v0 = bf2f(hbf[(int)((e0 & 0xFFFFu) << 6) + lane]);
    float v1 = bf2f(hbf[(int)((e1 & 0xFFFFu) << 6) + lane]);
    float v2 = bf2f(hbf[(int)((e2 & 0xFFFFu) << 6) + lane]);
    float v3 = bf2f(hbf[(int)((e3 & 0xFFFFu) << 6) + lane]);
    float v4 = bf2f(hbf[(int)((e4 & 0xFFFFu) << 6) + lane]);
    float v5 = bf2f(hbf[(int)((e5 & 0xFFFFu) << 6) + lane]);
    float v6 = bf2f(hbf[(int)((e6 & 0xFFFFu) << 6) + lane]);
    float v7 = bf2f(hbf[(int)((e7 & 0xFFFFu) << 6) + lane]);
    ACC(e0, v0) ACC(e1, v1) ACC(e2, v2) ACC(e3, v3)
    ACC(e4, v4) ACC(e5, v5) ACC(e6, v6) ACC(e7, v7)
  }
  for (; i < cnt; i++) {
    uint32_t e = cp[i];
    float v = bf2f(hbf[(int)((e & 0xFFFFu) << 6) + lane]);
    ACC(e, v)
  }
  float* mb = mbuf + (size_t)n * 192;
  mb[lane]       = a0 * (1.0f / (float)(c0 > 1 ? c0 : 1));
  mb[64 + lane]  = a1 * (1.0f / (float)(c1 > 1 ? c1 : 1));
  mb[128 + lane] = a2 * (1.0f / (float)(c2 > 1 ? c2 : 1));
}

// ---------------------------------------------------------------------------
// Transform GEMM (layer 1): f32; epilogue writes f32 h + bf16 shadow
// ---------------------------------------------------------------------------
__global__ __launch_bounds__(256) void k_gemm(const float* __restrict__ hin,
                                              const float* __restrict__ mbuf,
                                              const float* __restrict__ W,
                                              const float* __restrict__ root,
                                              const float* __restrict__ b,
                                              float* __restrict__ hout,
                                              uint16_t* __restrict__ hbf) {
  __shared__ float As[64 * 84];
  __shared__ float Bs[64 * 64];
  __shared__ float sb[64];
  int t = threadIdx.x;
  int bn = blockIdx.x * 64;
  if (t < 64) sb[t] = b[t];
  int tn = t & 15, to = t >> 4;
  float acc[4][4] = {};
  for (int kb = 0; kb < 4; kb++) {
    const float4* Bsrc = (const float4*)((kb == 0) ? root : (W + (size_t)(kb - 1) * 4096));
    for (int i2 = t; i2 < 1024; i2 += 256) ((float4*)Bs)[i2] = Bsrc[i2];
    int r = t >> 2;
    int node = bn + r;
    bool ok = node < N_NODES;
    const float* Arow = (kb == 0) ? (hin + (size_t)node * 64)
                                  : (mbuf + (size_t)node * 192 + (size_t)(kb - 1) * 64);
    #pragma unroll
    for (int ii = 0; ii < 4; ii++) {
      int c4 = (t & 3) + 4 * ii;
      float4 v = ok ? ((const float4*)Arow)[c4] : make_float4(0, 0, 0, 0);
      *(float4*)&As[r * 84 + c4 * 4] = v;
    }
    __syncthreads();
    #pragma unroll
    for (int k4 = 0; k4 < 16; k4++) {
      float4 a0 = *(const float4*)&As[(tn)      * 84 + k4 * 4];
      float4 a1 = *(const float4*)&As[(tn + 16) * 84 + k4 * 4];
      float4 a2 = *(const float4*)&As[(tn + 32) * 84 + k4 * 4];
      float4 a3 = *(const float4*)&As[(tn + 48) * 84 + k4 * 4];
      float4 b0 = *(const float4*)&Bs[(k4 * 4 + 0) * 64 + to * 4];
      float4 b1 = *(const float4*)&Bs[(k4 * 4 + 1) * 64 + to * 4];
      float4 b2 = *(const float4*)&Bs[(k4 * 4 + 2) * 64 + to * 4];
      float4 b3 = *(const float4*)&Bs[(k4 * 4 + 3) * 64 + to * 4];
      const float* av[4] = {&a0.x, &a1.x, &a2.x, &a3.x};
      const float* bv[4] = {&b0.x, &b1.x, &b2.x, &b3.x};
      #pragma unroll
      for (int c = 0; c < 4; c++)
        #pragma unroll
        for (int i3 = 0; i3 < 4; i3++)
          #pragma unroll
          for (int j = 0; j < 4; j++)
            acc[i3][j] = fmaf(av[i3][c], bv[c][j], acc[i3][j]);
    }
    __syncthreads();
  }
  #pragma unroll
  for (int i3 = 0; i3 < 4; i3++) {
    int node = bn + tn + 16 * i3;
    if (node < N_NODES) {
      float4 o;
      o.x = fmaxf(acc[i3][0] + sb[to * 4 + 0], 0.0f);
      o.y = fmaxf(acc[i3][1] + sb[to * 4 + 1], 0.0f);
      o.z = fmaxf(acc[i3][2] + sb[to * 4 + 2], 0.0f);
      o.w = fmaxf(acc[i3][3] + sb[to * 4 + 3], 0.0f);
      *(float4*)(hout + (size_t)node * 64 + to * 4) = o;
      uint2 pk;
      pk.x = (uint32_t)f2bf(o.x) | ((uint32_t)f2bf(o.y) << 16);
      pk.y = (uint32_t)f2bf(o.z) | ((uint32_t)f2bf(o.w) << 16);
      *(uint2*)(hbf + (size_t)node * 64 + to * 4) = pk;
    }
  }
}

// ---------------------------------------------------------------------------
// Final layer GEMM fused with P/Q projection:
//   h = relu(A_cat @ Wcat + b)   (kept only in LDS)
//   P = h @ dw1[0:64]  + db1 ;  Q = h @ dw1[64:128]   (written as bf16)
// ---------------------------------------------------------------------------
__global__ __launch_bounds__(256) void k_gemm_pq(const float* __restrict__ hin,
                                                 const float* __restrict__ mbuf,
                                                 const float* __restrict__ W,
                                                 const float* __restrict__ root,
                                                 const float* __restrict__ b,
                                                 const float* __restrict__ dw1,
                                                 const float* __restrict__ db1,
                                                 uint16_t* __restrict__ Pb,
                                                 uint16_t* __restrict__ Qb) {
  __shared__ float As[64 * 84];
  __shared__ float Bs[64 * 64];
  __shared__ float sb[64];
  __shared__ float sdb1[32];
  int t = threadIdx.x;
  int bn = blockIdx.x * 64;
  if (t < 64) sb[t] = b[t];
  else if (t < 96) sdb1[t - 64] = db1[t - 64];
  int tn = t & 15, to = t >> 4;
  float acc[4][4] = {};
  for (int kb = 0; kb < 4; kb++) {
    const float4* Bsrc = (const float4*)((kb == 0) ? root : (W + (size_t)(kb - 1) * 4096));
    for (int i2 = t; i2 < 1024; i2 += 256) ((float4*)Bs)[i2] = Bsrc[i2];
    int r = t >> 2;
    int node = bn + r;
    bool ok = node < N_NODES;
    const float* Arow = (kb == 0) ? (hin + (size_t)node * 64)
                                  : (mbuf + (size_t)node * 192 + (size_t)(kb - 1) * 64);
    #pragma unroll
    for (int ii = 0; ii < 4; ii++) {
      int c4 = (t & 3) + 4 * ii;
      float4 v = ok ? ((const float4*)Arow)[c4] : make_float4(0, 0, 0, 0);
      *(float4*)&As[r * 84 + c4 * 4] = v;
    }
    __syncthreads();
    #pragma unroll
    for (int k4 = 0; k4 < 16; k4++) {
      float4 a0 = *(const float4*)&As[(tn)      * 84 + k4 * 4];
      float4 a1 = *(const float4*)&As[(tn + 16) * 84 + k4 * 4];
      float4 a2 = *(const float4*)&As[(tn + 32) * 84 + k4 * 4];
      float4 a3 = *(const float4*)&As[(tn + 48) * 84 + k4 * 4];
      float4 b0 = *(const float4*)&Bs[(k4 * 4 + 0) * 64 + to * 4];
      float4 b1 = *(const float4*)&Bs[(k4 * 4 + 1) * 64 + to * 4];
      float4 b2 = *(const float4*)&Bs[(k4 * 4 + 2) * 64 + to * 4];
      float4 b3 = *(const float4*)&Bs[(k4 * 4 + 3) * 64 + to * 4];
      const float* av[4] = {&a0.x, &a1.x, &a2.x, &a3.x};
      const float* bv[4] = {&b0.x, &b1.x, &b2.x, &b3.x};
      #pragma unroll
      for (int c = 0; c < 4; c++)
        #pragma unroll
        for (int i3 = 0; i3 < 4; i3++)
          #pragma unroll
          for (int j = 0; j < 4; j++)
            acc[i3][j] = fmaf(av[i3][c], bv[c][j], acc[i3][j]);
    }
    __syncthreads();
  }
  // epilogue 1: h = relu(acc + b) -> As (rows tn+16i, cols to*4..+3)
  #pragma unroll
  for (int i3 = 0; i3 < 4; i3++) {
    int r = tn + 16 * i3;
    float4 o;
    o.x = fmaxf(acc[i3][0] + sb[to * 4 + 0], 0.0f);
    o.y = fmaxf(acc[i3][1] + sb[to * 4 + 1], 0.0f);
    o.z = fmaxf(acc[i3][2] + sb[to * 4 + 2], 0.0f);
    o.w = fmaxf(acc[i3][3] + sb[to * 4 + 3], 0.0f);
    *(float4*)&As[r * 84 + to * 4] = o;
  }
  // load D = [A | B] (64 x 64) from dw1 into Bs
  for (int i = t; i < 4096; i += 256) {
    int k = i >> 6, j = i & 63;
    Bs[i] = (j < 32) ? dw1[k * 32 + j] : dw1[2048 + k * 32 + (j - 32)];
  }
  __syncthreads();
  // mini-GEMM: [64x64] @ [64x64], K=64
  float acc2[4][4] = {};
  #pragma unroll
  for (int k4 = 0; k4 < 16; k4++) {
    float4 a0 = *(const float4*)&As[(tn)      * 84 + k4 * 4];
    float4 a1 = *(const float4*)&As[(tn + 16) * 84 + k4 * 4];
    float4 a2 = *(const float4*)&As[(tn + 32) * 84 + k4 * 4];
    float4 a3 = *(const float4*)&As[(tn + 48) * 84 + k4 * 4];
    float4 b0 = *(const float4*)&Bs[(k4 * 4 + 0) * 64 + to * 4];
    float4 b1 = *(const float4*)&Bs[(k4 * 4 + 1) * 64 + to * 4];
    float4 b2 = *(const float4*)&Bs[(k4 * 4 + 2) * 64 + to * 4];
    float4 b3 = *(const float4*)&Bs[(k4 * 4 + 3) * 64 + to * 4];
    const float* av[4] = {&a0.x, &a1.x, &a2.x, &a3.x};
    const float* bv[4] = {&b0.x, &b1.x, &b2.x, &b3.x};
    #pragma unroll
    for (int c = 0; c < 4; c++)
      #pragma unroll
      for (int i3 = 0; i3 < 4; i3++)
        #pragma unroll
        for (int j = 0; j < 4; j++)
          acc2[i3][j] = fmaf(av[i3][c], bv[c][j], acc2[i3][j]);
  }
  // epilogue 2: cols 0..31 -> P (+db1), cols 32..63 -> Q ; bf16 packed
  bool isP = (to < 8);
  float bias[4];
  #pragma unroll
  for (int j = 0; j < 4; j++) bias[j] = isP ? sdb1[to * 4 + j] : 0.0f;
  #pragma unroll
  for (int i3 = 0; i3 < 4; i3++) {
    int node = bn + tn + 16 * i3;
    if (node < N_NODES) {
      float v0 = acc2[i3][0] + bias[0];
      float v1 = acc2[i3][1] + bias[1];
      float v2 = acc2[i3][2] + bias[2];
      float v3 = acc2[i3][3] + bias[3];
      uint2 pk;
      pk.x = (uint32_t)f2bf(v0) | ((uint32_t)f2bf(v1) << 16);
      pk.y = (uint32_t)f2bf(v2) | ((uint32_t)f2bf(v3) << 16);
      if (isP) *(uint2*)(Pb + (size_t)node * 32 + to * 4) = pk;
      else     *(uint2*)(Qb + (size_t)node * 32 + (to - 8) * 4) = pk;
    }
  }
}

// ---------------------------------------------------------------------------
// Decoder edge pass: bf16 P/Q gathers (one 64 B line per row)
// ---------------------------------------------------------------------------
__global__ __launch_bounds__(256) void k_dec(const int* __restrict__ ei,
                                             const float* __restrict__ ea,
                                             const uint16_t* __restrict__ Pb,
                                             const uint16_t* __restrict__ Qb,
                                             const float* __restrict__ dw1,
                                             const float* __restrict__ dw2,
                                             const float* __restrict__ db2,
                                             const float* __restrict__ dw3,
                                             const float* __restrict__ db3,
                                             float* __restrict__ out) {
  __shared__ float C[6 * 32], W2[32 * 16], sb2[16], W3[16];
  __shared__ float sb3;
  int t = threadIdx.x;
  for (int i = t; i < 192; i += 256) C[i] = dw1[128 * 32 + i];
  for (int i = t; i < 512; i += 256) W2[i] = dw2[i];
  if (t < 16) { sb2[t] = db2[t]; W3[t] = dw3[t]; }
  if (t == 0) sb3 = db3[0];
  __syncthreads();
  int e = blockIdx.x * 256 + t;
  int s = ei[e];
  int d = ei[N_EDGES + e];
  float ea6[6];
  #pragma unroll
  for (int i = 0; i < 6; i++) ea6[i] = ea[(size_t)e * 6 + i];
  const uint4* Ps = (const uint4*)(Pb + (size_t)s * 32);
  const uint4* Qd = (const uint4*)(Qb + (size_t)d * 32);
  float z1[32];
  #pragma unroll
  for (int j4 = 0; j4 < 4; j4++) {
    uint4 pv = Ps[j4];
    uint4 qv = Qd[j4];
    const uint32_t* pw = &pv.x;
    const uint32_t* qw = &qv.x;
    #pragma unroll
    for (int c = 0; c < 4; c++) {
      int j = j4 * 8 + c * 2;
      float vlo = bflo(pw[c]) + bflo(qw[c]);
      float vhi = bfhi(pw[c]) + bfhi(qw[c]);
      #pragma unroll
      for (int k = 0; k < 6; k++) {
        vlo = fmaf(ea6[k], C[k * 32 + j], vlo);
        vhi = fmaf(ea6[k], C[k * 32 + j + 1], vhi);
      }
      z1[j]     = fmaxf(vlo, 0.0f);
      z1[j + 1] = fmaxf(vhi, 0.0f);
    }
  }
  float o = sb3;
  #pragma unroll
  for (int i = 0; i < 16; i++) {
    float z = sb2[i];
    #pragma unroll
    for (int j = 0; j < 32; j++) z = fmaf(z1[j], W2[j * 16 + i], z);
    o = fmaf(fmaxf(z, 0.0f), W3[i], o);
  }
  out[e] = o;
}

// ---------------------------------------------------------------------------
extern "C" void kernel_launch(void* const* d_in, const int* in_sizes, int n_in,
                              void* d_out, int out_size, void* d_ws, size_t ws_size,
                              hipStream_t stream) {
  const float* x      = (const float*)d_in[0];
  const int*   ei     = (const int*)d_in[1];
  const float* ea     = (const float*)d_in[2];
  const float* w0     = (const float*)d_in[3];
  const float* root0  = (const float*)d_in[4];
  const float* b0     = (const float*)d_in[5];
  const float* w1     = (const float*)d_in[6];
  const float* root1  = (const float*)d_in[7];
  const float* b1     = (const float*)d_in[8];
  const float* w2     = (const float*)d_in[9];
  const float* root2  = (const float*)d_in[10];
  const float* b2     = (const float*)d_in[11];
  const float* dw1    = (const float*)d_in[12];
  const float* db1    = (const float*)d_in[13];
  const float* dw2    = (const float*)d_in[14];
  const float* db2    = (const float*)d_in[15];
  const float* dw3    = (const float*)d_in[16];
  const float* db3    = (const float*)d_in[17];
  float* out = (float*)d_out;

  char* w = (char*)d_ws;
  int* cnt3        = (int*)w;       w += (size_t)N_NODES * 3 * 4;
  int* bcur        = (int*)w;       w += (size_t)NB * 4;
  int4* meta       = (int4*)w;      w += (size_t)N_NODES * 16;
  uint32_t* csr    = (uint32_t*)w;  w += (size_t)N_EDGES * 4;
  float4* x4       = (float4*)w;    w += (size_t)N_NODES * 16;
  float* h1        = (float*)w;     w += (size_t)N_NODES * 64 * 4;
  float* h2        = (float*)w;     w += (size_t)N_NODES * 64 * 4;
  float* mbuf      = (float*)w;     w += (size_t)N_NODES * 192 * 4;
  uint16_t* hbf1   = (uint16_t*)w;  w += (size_t)N_NODES * 64 * 2;
  uint16_t* hbf2   = (uint16_t*)w;  w += (size_t)N_NODES * 64 * 2;
  // Pb/Qb live in hbf1/hbf2 (dead after the k_agg that consumes each)
  uint16_t* Pb     = hbf1;
  uint16_t* Qb     = hbf2;
  // pairbuf (12.81 MB) aliases h1 + head of h2 (dead until layer kernels)
  uint32_t* pairbuf = (uint32_t*)h1;
  // excl/bsum alias mbuf (dead until first k_agg)
  int* excl        = (int*)mbuf;
  int* bsum        = (int*)mbuf + N_NODES;

  hipMemsetAsync(cnt3, 0, (size_t)(N_NODES * 3 + NB) * 4, stream);

  k_prep   <<<NWG_PREP, 256, 0, stream>>>(ei, ea, cnt3, bcur, pairbuf);
  k_scanA  <<<NBLK_N, 256, 0, stream>>>(cnt3, excl, bsum);
  k_scanB  <<<1, 256, 0, stream>>>(bsum);
  k_scanC  <<<NBLK_N, 256, 0, stream>>>(cnt3, excl, bsum, meta, x, x4);
  k_scat2  <<<NB, 256, 0, stream>>>(pairbuf, bcur, meta, csr);

  k_layer0 <<<N_NODES / 4, 256, 0, stream>>>(x4, w0, root0, b0, meta, csr, h1, hbf1);

  k_agg    <<<N_NODES / 4, 256, 0, stream>>>(hbf1, meta, csr, mbuf);
  k_gemm   <<<(N_NODES + 63) / 64, 256, 0, stream>>>(h1, mbuf, w1, root1, b1, h2, hbf2);

  k_agg    <<<N_NODES / 4, 256, 0, stream>>>(hbf2, meta, csr, mbuf);
  // final layer + P/Q projection fused; h3 never materialized
  k_gemm_pq<<<(N_NODES + 63) / 64, 256, 0, stream>>>(h2, mbuf, w2, root2, b2,
                                                     dw1, db1, Pb, Qb);

  k_dec    <<<N_EDGES / 256, 256, 0, stream>>>(ei, ea, Pb, Qb, dw1, dw2, db2, dw3, db3, out);
}

// Round 7
// 432.428 us; speedup vs baseline: 3.8716x; 1.0431x over previous
//
#include <hip/hip_runtime.h>
#include <stdint.h>

#define N_NODES 50000
#define N_EDGES 1600000
#define NBLK_N 196        // ceil(50000/256)
#define NB 391            // buckets of 128 dst nodes
#define BPAD 8192         // padded bucket capacity
#define CHUNK 2048        // edges per prep workgroup
#define NWG_PREP 782      // ceil(1.6M/2048)

__device__ inline float bf2f(uint16_t u) {
  union { uint32_t i; float f; } c; c.i = (uint32_t)u << 16; return c.f;
}
__device__ inline uint16_t f2bf(float f) {
  union { uint32_t i; float f; } c; c.f = f;
  uint32_t b = c.i;
  b += 0x7FFFu + ((b >> 16) & 1u);   // round to nearest even
  return (uint16_t)(b >> 16);
}
__device__ inline float bflo(uint32_t w) {
  union { uint32_t i; float f; } c; c.i = w << 16; return c.f;
}
__device__ inline float bfhi(uint32_t w) {
  union { uint32_t i; float f; } c; c.i = w & 0xFFFF0000u; return c.f;
}

// ---------------------------------------------------------------------------
// Prep + pass-1 binning
// ---------------------------------------------------------------------------
__global__ __launch_bounds__(256) void k_prep(const int* __restrict__ ei,
                                              const float* __restrict__ ea,
                                              int* __restrict__ cnt3,
                                              int* __restrict__ bcur,
                                              uint32_t* __restrict__ pairbuf) {
  __shared__ int hist[NB];
  __shared__ int hbase[NB];
  int t = threadIdx.x;
  int base = blockIdx.x * CHUNK;
  for (int i = t; i < NB; i += 256) hist[i] = 0;
  __syncthreads();

  uint32_t wreg[8];
  int breg[8];
  #pragma unroll
  for (int k = 0; k < 8; k++) {
    int e = base + t + k * 256;
    breg[k] = -1;
    if (e < N_EDGES) {
      float dist = ea[(size_t)e * 6];
      int rel = (dist > 5000.0f) + (dist > 10000.0f);
      int s = ei[e];
      int d = ei[N_EDGES + e];
      wreg[k] = (uint32_t)s | ((uint32_t)rel << 16) | ((uint32_t)(d & 127) << 24);
      breg[k] = d >> 7;
      atomicAdd(&cnt3[d * 3 + rel], 1);
      atomicAdd(&hist[breg[k]], 1);
    }
  }
  __syncthreads();
  for (int i = t; i < NB; i += 256) {
    int h = hist[i];
    hbase[i] = h ? atomicAdd(&bcur[i], h) : 0;
    hist[i] = 0;
  }
  __syncthreads();
  #pragma unroll
  for (int k = 0; k < 8; k++) {
    int b = breg[k];
    if (b >= 0) {
      int r = atomicAdd(&hist[b], 1);
      pairbuf[(size_t)b * BPAD + hbase[b] + r] = wreg[k];
    }
  }
}

// ---------------------------------------------------------------------------
// Parallel scan of node degrees
// ---------------------------------------------------------------------------
__global__ __launch_bounds__(256) void k_scanA(const int* __restrict__ cnt3,
                                               int* __restrict__ excl,
                                               int* __restrict__ bsum) {
  __shared__ int s[256];
  int t = threadIdx.x;
  int n = blockIdx.x * 256 + t;
  int deg = 0;
  if (n < N_NODES) deg = cnt3[3 * n] + cnt3[3 * n + 1] + cnt3[3 * n + 2];
  s[t] = deg;
  __syncthreads();
  for (int ofs = 1; ofs < 256; ofs <<= 1) {
    int v = (t >= ofs) ? s[t - ofs] : 0;
    __syncthreads();
    s[t] += v;
    __syncthreads();
  }
  if (n < N_NODES) excl[n] = s[t] - deg;
  if (t == 255) bsum[blockIdx.x] = s[255];
}

__global__ __launch_bounds__(256) void k_scanB(int* __restrict__ bsum) {
  __shared__ int s[256];
  int t = threadIdx.x;
  int v = (t < NBLK_N) ? bsum[t] : 0;
  s[t] = v;
  __syncthreads();
  for (int ofs = 1; ofs < 256; ofs <<= 1) {
    int u = (t >= ofs) ? s[t - ofs] : 0;
    __syncthreads();
    s[t] += u;
    __syncthreads();
  }
  if (t < NBLK_N) bsum[t] = s[t] - v;   // exclusive
}

__global__ __launch_bounds__(256) void k_scanC(const int* __restrict__ cnt3,
                                               const int* __restrict__ excl,
                                               const int* __restrict__ bsum,
                                               int4* __restrict__ meta,
                                               const float* __restrict__ x,
                                               float4* __restrict__ x4) {
  int n = blockIdx.x * 256 + threadIdx.x;
  if (n >= N_NODES) return;
  meta[n] = make_int4(bsum[blockIdx.x] + excl[n],
                      cnt3[3 * n], cnt3[3 * n + 1], cnt3[3 * n + 2]);
  x4[n] = make_float4(x[n * 3], x[n * 3 + 1], x[n * 3 + 2], 0.0f);
}

// ---------------------------------------------------------------------------
// Pass-2 scatter
// ---------------------------------------------------------------------------
__global__ __launch_bounds__(256) void k_scat2(const uint32_t* __restrict__ pairbuf,
                                               const int* __restrict__ bcur,
                                               const int4* __restrict__ meta,
                                               uint32_t* __restrict__ csr) {
  __shared__ int lcur[128];
  int b = blockIdx.x;
  int t = threadIdx.x;
  int node0 = b << 7;
  if (t < 128) {
    int n = node0 + t;
    lcur[t] = (n < N_NODES) ? meta[n].x : 0;
  }
  int cnt = bcur[b];
  __syncthreads();
  const uint32_t* pb = pairbuf + (size_t)b * BPAD;
  for (int i = t; i < cnt; i += 256) {
    uint32_t w = pb[i];
    int dl = (int)(w >> 24);
    int p = atomicAdd(&lcur[dl], 1);
    csr[p] = w & 0x00FFFFFFu;   // src | rel<<16
  }
}

// ---------------------------------------------------------------------------
// Layer 0: din=3. Wave per node; writes f32 h + bf16 shadow.
// ---------------------------------------------------------------------------
__global__ __launch_bounds__(256) void k_layer0(const float4* __restrict__ x4,
                                                const float* __restrict__ W0,
                                                const float* __restrict__ root0,
                                                const float* __restrict__ b0,
                                                const int4* __restrict__ meta,
                                                const uint32_t* __restrict__ csr,
                                                float* __restrict__ hout,
                                                uint16_t* __restrict__ hbf) {
  __shared__ float sW[576], sR[192], sb[64];
  int t = threadIdx.x;
  for (int i = t; i < 576; i += 256) sW[i] = W0[i];
  for (int i = t; i < 192; i += 256) sR[i] = root0[i];
  if (t < 64) sb[t] = b0[t];
  __syncthreads();
  int wid = t >> 6, lane = t & 63;
  int n = blockIdx.x * 4 + wid;
  int4 md = meta[n];
  int off = md.x, c0 = md.y, c1 = md.z, c2 = md.w;
  int cnt = c0 + c1 + c2;
  float a00 = 0, a01 = 0, a02 = 0, a10 = 0, a11 = 0, a12 = 0, a20 = 0, a21 = 0, a22 = 0;
  for (int base = 0; base < cnt; base += 64) {
    int idx = base + lane;
    float4 v = make_float4(0, 0, 0, 0);
    int r = 3;
    if (idx < cnt) {
      uint32_t u = csr[off + idx];
      r = (int)(u >> 16);
      v = x4[u & 0xFFFFu];
    }
    a00 += (r == 0) ? v.x : 0.0f; a01 += (r == 0) ? v.y : 0.0f; a02 += (r == 0) ? v.z : 0.0f;
    a10 += (r == 1) ? v.x : 0.0f; a11 += (r == 1) ? v.y : 0.0f; a12 += (r == 1) ? v.z : 0.0f;
    a20 += (r == 2) ? v.x : 0.0f; a21 += (r == 2) ? v.y : 0.0f; a22 += (r == 2) ? v.z : 0.0f;
  }
  #pragma unroll
  for (int d = 1; d < 64; d <<= 1) {
    a00 += __shfl_xor(a00, d); a01 += __shfl_xor(a01, d); a02 += __shfl_xor(a02, d);
    a10 += __shfl_xor(a10, d); a11 += __shfl_xor(a11, d); a12 += __shfl_xor(a12, d);
    a20 += __shfl_xor(a20, d); a21 += __shfl_xor(a21, d); a22 += __shfl_xor(a22, d);
  }
  float i0 = 1.0f / (float)(c0 > 1 ? c0 : 1);
  float i1 = 1.0f / (float)(c1 > 1 ? c1 : 1);
  float i2 = 1.0f / (float)(c2 > 1 ? c2 : 1);
  float4 xn = x4[n];
  float in[12];
  in[0] = xn.x; in[1] = xn.y; in[2] = xn.z;
  in[3] = a00 * i0; in[4] = a01 * i0; in[5] = a02 * i0;
  in[6] = a10 * i1; in[7] = a11 * i1; in[8] = a12 * i1;
  in[9] = a20 * i2; in[10] = a21 * i2; in[11] = a22 * i2;
  float acc = sb[lane];
  #pragma unroll
  for (int k = 0; k < 3; k++) acc = fmaf(in[k], sR[k * 64 + lane], acc);
  #pragma unroll
  for (int k = 0; k < 9; k++) acc = fmaf(in[3 + k], sW[k * 64 + lane], acc);
  float h = fmaxf(acc, 0.0f);
  hout[(size_t)n * 64 + lane] = h;
  hbf[(size_t)n * 64 + lane] = f2bf(h);
}

// ---------------------------------------------------------------------------
// Aggregation: wave per node, lane = feature, bf16 gathers (128 B/edge).
// ---------------------------------------------------------------------------
#define ACC(E, V) { int r_ = (int)((E) >> 16); \
  a0 += (r_ == 0) ? (V) : 0.0f; a1 += (r_ == 1) ? (V) : 0.0f; a2 += (r_ == 2) ? (V) : 0.0f; }

__global__ __launch_bounds__(256) void k_agg(const uint16_t* __restrict__ hbf,
                                             const int4* __restrict__ meta,
                                             const uint32_t* __restrict__ csr,
                                             float* __restrict__ mbuf) {
  int t = threadIdx.x, wid = t >> 6, lane = t & 63;
  int n = blockIdx.x * 4 + wid;
  int4 md = meta[n];
  int off = __builtin_amdgcn_readfirstlane(md.x);
  int c0  = __builtin_amdgcn_readfirstlane(md.y);
  int c1  = __builtin_amdgcn_readfirstlane(md.z);
  int c2  = __builtin_amdgcn_readfirstlane(md.w);
  int cnt = c0 + c1 + c2;
  const uint32_t* cp = csr + off;
  float a0 = 0, a1 = 0, a2 = 0;
  int i = 0;
  for (; i + 8 <= cnt; i += 8) {
    uint32_t e0 = cp[i],     e1 = cp[i + 1], e2 = cp[i + 2], e3 = cp[i + 3];
    uint32_t e4 = cp[i + 4], e5 = cp[i + 5], e6 = cp[i + 6], e7 = cp[i + 7];
    float v0 = bf2f(hbf[(int)((e0 & 0xFFFFu) << 6) + lane]);
    float v1 = bf2f(hbf[(int)((e1 & 0xFFFFu) << 6) + lane]);
    float v2 = bf2f(hbf[(int)((e2 & 0xFFFFu) << 6) + lane]);
    float v3 = bf2f(hbf[(int)((e3 & 0xFFFFu) << 6) + lane]);
    float v4 = bf2f(hbf[(int)((e4 & 0xFFFFu) << 6) + lane]);
    float v5 = bf2f(hbf[(int)((e5 & 0xFFFFu) << 6) + lane]);
    float v6 = bf2f(hbf[(int)((e6 & 0xFFFFu) << 6) + lane]);
    float v7 = bf2f(hbf[(int)((e7 & 0xFFFFu) << 6) + lane]);
    ACC(e0, v0) ACC(e1, v1) ACC(e2, v2) ACC(e3, v3)
    ACC(e4, v4) ACC(e5, v5) ACC(e6, v6) ACC(e7, v7)
  }
  for (; i < cnt; i++) {
    uint32_t e = cp[i];
    float v = bf2f(hbf[(int)((e & 0xFFFFu) << 6) + lane]);
    ACC(e, v)
  }
  float* mb = mbuf + (size_t)n * 192;
  mb[lane]       = a0 * (1.0f / (float)(c0 > 1 ? c0 : 1));
  mb[64 + lane]  = a1 * (1.0f / (float)(c1 > 1 ? c1 : 1));
  mb[128 + lane] = a2 * (1.0f / (float)(c2 > 1 ? c2 : 1));
}

// ---------------------------------------------------------------------------
// Transform GEMM: f32; epilogue writes f32 h (+ optional bf16 shadow)
// ---------------------------------------------------------------------------
__global__ __launch_bounds__(256) void k_gemm(const float* __restrict__ hin,
                                              const float* __restrict__ mbuf,
                                              const float* __restrict__ W,
                                              const float* __restrict__ root,
                                              const float* __restrict__ b,
                                              float* __restrict__ hout,
                                              uint16_t* __restrict__ hbf) {
  __shared__ float As[64 * 84];
  __shared__ float Bs[64 * 64];
  __shared__ float sb[64];
  int t = threadIdx.x;
  int bn = blockIdx.x * 64;
  if (t < 64) sb[t] = b[t];
  int tn = t & 15, to = t >> 4;
  float acc[4][4] = {};
  for (int kb = 0; kb < 4; kb++) {
    const float4* Bsrc = (const float4*)((kb == 0) ? root : (W + (size_t)(kb - 1) * 4096));
    for (int i2 = t; i2 < 1024; i2 += 256) ((float4*)Bs)[i2] = Bsrc[i2];
    int r = t >> 2;
    int node = bn + r;
    bool ok = node < N_NODES;
    const float* Arow = (kb == 0) ? (hin + (size_t)node * 64)
                                  : (mbuf + (size_t)node * 192 + (size_t)(kb - 1) * 64);
    #pragma unroll
    for (int ii = 0; ii < 4; ii++) {
      int c4 = (t & 3) + 4 * ii;
      float4 v = ok ? ((const float4*)Arow)[c4] : make_float4(0, 0, 0, 0);
      *(float4*)&As[r * 84 + c4 * 4] = v;
    }
    __syncthreads();
    #pragma unroll
    for (int k4 = 0; k4 < 16; k4++) {
      float4 a0 = *(const float4*)&As[(tn)      * 84 + k4 * 4];
      float4 a1 = *(const float4*)&As[(tn + 16) * 84 + k4 * 4];
      float4 a2 = *(const float4*)&As[(tn + 32) * 84 + k4 * 4];
      float4 a3 = *(const float4*)&As[(tn + 48) * 84 + k4 * 4];
      float4 b0 = *(const float4*)&Bs[(k4 * 4 + 0) * 64 + to * 4];
      float4 b1 = *(const float4*)&Bs[(k4 * 4 + 1) * 64 + to * 4];
      float4 b2 = *(const float4*)&Bs[(k4 * 4 + 2) * 64 + to * 4];
      float4 b3 = *(const float4*)&Bs[(k4 * 4 + 3) * 64 + to * 4];
      const float* av[4] = {&a0.x, &a1.x, &a2.x, &a3.x};
      const float* bv[4] = {&b0.x, &b1.x, &b2.x, &b3.x};
      #pragma unroll
      for (int c = 0; c < 4; c++)
        #pragma unroll
        for (int i3 = 0; i3 < 4; i3++)
          #pragma unroll
          for (int j = 0; j < 4; j++)
            acc[i3][j] = fmaf(av[i3][c], bv[c][j], acc[i3][j]);
    }
    __syncthreads();
  }
  #pragma unroll
  for (int i3 = 0; i3 < 4; i3++) {
    int node = bn + tn + 16 * i3;
    if (node < N_NODES) {
      float4 o;
      o.x = fmaxf(acc[i3][0] + sb[to * 4 + 0], 0.0f);
      o.y = fmaxf(acc[i3][1] + sb[to * 4 + 1], 0.0f);
      o.z = fmaxf(acc[i3][2] + sb[to * 4 + 2], 0.0f);
      o.w = fmaxf(acc[i3][3] + sb[to * 4 + 3], 0.0f);
      *(float4*)(hout + (size_t)node * 64 + to * 4) = o;
      if (hbf) {
        uint2 pk;
        pk.x = (uint32_t)f2bf(o.x) | ((uint32_t)f2bf(o.y) << 16);
        pk.y = (uint32_t)f2bf(o.z) | ((uint32_t)f2bf(o.w) << 16);
        *(uint2*)(hbf + (size_t)node * 64 + to * 4) = pk;
      }
    }
  }
}

// ---------------------------------------------------------------------------
// P/Q projection GEMM: [64-node tile] x [dw1_A | dw1_B] (64x64), K=64.
// P = h @ dw1[0:64] + db1 ; Q = h @ dw1[64:128].  bf16 outputs.
// ---------------------------------------------------------------------------
__global__ __launch_bounds__(256) void k_pq2(const float* __restrict__ h,
                                             const float* __restrict__ dw1,
                                             const float* __restrict__ db1,
                                             uint16_t* __restrict__ Pb,
                                             uint16_t* __restrict__ Qb) {
  __shared__ float As[64 * 84];
  __shared__ float Bs[64 * 64];
  __shared__ float sdb1[32];
  int t = threadIdx.x;
  int bn = blockIdx.x * 64;
  if (t < 32) sdb1[t] = db1[t];
  {
    int r = t >> 2;
    int node = bn + r;
    bool ok = node < N_NODES;
    const float* Arow = h + (size_t)node * 64;
    #pragma unroll
    for (int ii = 0; ii < 4; ii++) {
      int c4 = (t & 3) + 4 * ii;
      float4 v = ok ? ((const float4*)Arow)[c4] : make_float4(0, 0, 0, 0);
      *(float4*)&As[r * 84 + c4 * 4] = v;
    }
  }
  // D[k][j] = j<32 ? dw1_A[k][j] : dw1_B[k][j-32]
  for (int i = t; i < 4096; i += 256) {
    int k = i >> 6, j = i & 63;
    Bs[i] = (j < 32) ? dw1[k * 32 + j] : dw1[(64 + k) * 32 + (j - 32)];
  }
  __syncthreads();
  int tn = t & 15, to = t >> 4;
  float acc[4][4] = {};
  #pragma unroll
  for (int k4 = 0; k4 < 16; k4++) {
    float4 a0 = *(const float4*)&As[(tn)      * 84 + k4 * 4];
    float4 a1 = *(const float4*)&As[(tn + 16) * 84 + k4 * 4];
    float4 a2 = *(const float4*)&As[(tn + 32) * 84 + k4 * 4];
    float4 a3 = *(const float4*)&As[(tn + 48) * 84 + k4 * 4];
    float4 b0 = *(const float4*)&Bs[(k4 * 4 + 0) * 64 + to * 4];
    float4 b1 = *(const float4*)&Bs[(k4 * 4 + 1) * 64 + to * 4];
    float4 b2 = *(const float4*)&Bs[(k4 * 4 + 2) * 64 + to * 4];
    float4 b3 = *(const float4*)&Bs[(k4 * 4 + 3) * 64 + to * 4];
    const float* av[4] = {&a0.x, &a1.x, &a2.x, &a3.x};
    const float* bv[4] = {&b0.x, &b1.x, &b2.x, &b3.x};
    #pragma unroll
    for (int c = 0; c < 4; c++)
      #pragma unroll
      for (int i3 = 0; i3 < 4; i3++)
        #pragma unroll
        for (int j = 0; j < 4; j++)
          acc[i3][j] = fmaf(av[i3][c], bv[c][j], acc[i3][j]);
  }
  bool isP = (to < 8);
  float bias0 = isP ? sdb1[to * 4 + 0] : 0.0f;
  float bias1 = isP ? sdb1[to * 4 + 1] : 0.0f;
  float bias2 = isP ? sdb1[to * 4 + 2] : 0.0f;
  float bias3 = isP ? sdb1[to * 4 + 3] : 0.0f;
  #pragma unroll
  for (int i3 = 0; i3 < 4; i3++) {
    int node = bn + tn + 16 * i3;
    if (node < N_NODES) {
      float v0 = acc[i3][0] + bias0;
      float v1 = acc[i3][1] + bias1;
      float v2 = acc[i3][2] + bias2;
      float v3 = acc[i3][3] + bias3;
      uint2 pk;
      pk.x = (uint32_t)f2bf(v0) | ((uint32_t)f2bf(v1) << 16);
      pk.y = (uint32_t)f2bf(v2) | ((uint32_t)f2bf(v3) << 16);
      if (isP) *(uint2*)(Pb + (size_t)node * 32 + to * 4) = pk;
      else     *(uint2*)(Qb + (size_t)node * 32 + (to - 8) * 4) = pk;
    }
  }
}

// ---------------------------------------------------------------------------
// Decoder edge pass: bf16 P/Q gathers (one 64 B line per row)
// ---------------------------------------------------------------------------
__global__ __launch_bounds__(256) void k_dec(const int* __restrict__ ei,
                                             const float* __restrict__ ea,
                                             const uint16_t* __restrict__ Pb,
                                             const uint16_t* __restrict__ Qb,
                                             const float* __restrict__ dw1,
                                             const float* __restrict__ dw2,
                                             const float* __restrict__ db2,
                                             const float* __restrict__ dw3,
                                             const float* __restrict__ db3,
                                             float* __restrict__ out) {
  __shared__ float C[6 * 32], W2[32 * 16], sb2[16], W3[16];
  __shared__ float sb3;
  int t = threadIdx.x;
  for (int i = t; i < 192; i += 256) C[i] = dw1[128 * 32 + i];
  for (int i = t; i < 512; i += 256) W2[i] = dw2[i];
  if (t < 16) { sb2[t] = db2[t]; W3[t] = dw3[t]; }
  if (t == 0) sb3 = db3[0];
  __syncthreads();
  int e = blockIdx.x * 256 + t;
  int s = ei[e];
  int d = ei[N_EDGES + e];
  float ea6[6];
  #pragma unroll
  for (int i = 0; i < 6; i++) ea6[i] = ea[(size_t)e * 6 + i];
  const uint4* Ps = (const uint4*)(Pb + (size_t)s * 32);
  const uint4* Qd = (const uint4*)(Qb + (size_t)d * 32);
  float z1[32];
  #pragma unroll
  for (int j4 = 0; j4 < 4; j4++) {
    uint4 pv = Ps[j4];
    uint4 qv = Qd[j4];
    const uint32_t* pw = &pv.x;
    const uint32_t* qw = &qv.x;
    #pragma unroll
    for (int c = 0; c < 4; c++) {
      int j = j4 * 8 + c * 2;
      float vlo = bflo(pw[c]) + bflo(qw[c]);
      float vhi = bfhi(pw[c]) + bfhi(qw[c]);
      #pragma unroll
      for (int k = 0; k < 6; k++) {
        vlo = fmaf(ea6[k], C[k * 32 + j], vlo);
        vhi = fmaf(ea6[k], C[k * 32 + j + 1], vhi);
      }
      z1[j]     = fmaxf(vlo, 0.0f);
      z1[j + 1] = fmaxf(vhi, 0.0f);
    }
  }
  float o = sb3;
  #pragma unroll
  for (int i = 0; i < 16; i++) {
    float z = sb2[i];
    #pragma unroll
    for (int j = 0; j < 32; j++) z = fmaf(z1[j], W2[j * 16 + i], z);
    o = fmaf(fmaxf(z, 0.0f), W3[i], o);
  }
  out[e] = o;
}

// ---------------------------------------------------------------------------
extern "C" void kernel_launch(void* const* d_in, const int* in_sizes, int n_in,
                              void* d_out, int out_size, void* d_ws, size_t ws_size,
                              hipStream_t stream) {
  const float* x      = (const float*)d_in[0];
  const int*   ei     = (const int*)d_in[1];
  const float* ea     = (const float*)d_in[2];
  const float* w0     = (const float*)d_in[3];
  const float* root0  = (const float*)d_in[4];
  const float* b0     = (const float*)d_in[5];
  const float* w1     = (const float*)d_in[6];
  const float* root1  = (const float*)d_in[7];
  const float* b1     = (const float*)d_in[8];
  const float* w2     = (const float*)d_in[9];
  const float* root2  = (const float*)d_in[10];
  const float* b2     = (const float*)d_in[11];
  const float* dw1    = (const float*)d_in[12];
  const float* db1    = (const float*)d_in[13];
  const float* dw2    = (const float*)d_in[14];
  const float* db2    = (const float*)d_in[15];
  const float* dw3    = (const float*)d_in[16];
  const float* db3    = (const float*)d_in[17];
  float* out = (float*)d_out;

  char* w = (char*)d_ws;
  int* cnt3        = (int*)w;       w += (size_t)N_NODES * 3 * 4;
  int* bcur        = (int*)w;       w += (size_t)NB * 4;
  int4* meta       = (int4*)w;      w += (size_t)N_NODES * 16;
  uint32_t* csr    = (uint32_t*)w;  w += (size_t)N_EDGES * 4;
  float4* x4       = (float4*)w;    w += (size_t)N_NODES * 16;
  float* h1        = (float*)w;     w += (size_t)N_NODES * 64 * 4;
  float* h2        = (float*)w;     w += (size_t)N_NODES * 64 * 4;
  float* mbuf      = (float*)w;     w += (size_t)N_NODES * 192 * 4;
  uint16_t* hbf1   = (uint16_t*)w;  w += (size_t)N_NODES * 64 * 2;
  uint16_t* hbf2   = (uint16_t*)w;  w += (size_t)N_NODES * 64 * 2;
  // Pb/Qb live in hbf1/hbf2 (dead after the k_agg that consumes each)
  uint16_t* Pb     = hbf1;
  uint16_t* Qb     = hbf2;
  // pairbuf (12.81 MB) aliases h1 + head of h2 (dead until layer kernels)
  uint32_t* pairbuf = (uint32_t*)h1;
  // excl/bsum alias mbuf (dead until first k_agg)
  int* excl        = (int*)mbuf;
  int* bsum        = (int*)mbuf + N_NODES;

  hipMemsetAsync(cnt3, 0, (size_t)(N_NODES * 3 + NB) * 4, stream);

  k_prep   <<<NWG_PREP, 256, 0, stream>>>(ei, ea, cnt3, bcur, pairbuf);
  k_scanA  <<<NBLK_N, 256, 0, stream>>>(cnt3, excl, bsum);
  k_scanB  <<<1, 256, 0, stream>>>(bsum);
  k_scanC  <<<NBLK_N, 256, 0, stream>>>(cnt3, excl, bsum, meta, x, x4);
  k_scat2  <<<NB, 256, 0, stream>>>(pairbuf, bcur, meta, csr);

  k_layer0 <<<N_NODES / 4, 256, 0, stream>>>(x4, w0, root0, b0, meta, csr, h1, hbf1);

  k_agg    <<<N_NODES / 4, 256, 0, stream>>>(hbf1, meta, csr, mbuf);
  k_gemm   <<<(N_NODES + 63) / 64, 256, 0, stream>>>(h1, mbuf, w1, root1, b1, h2, hbf2);

  k_agg    <<<N_NODES / 4, 256, 0, stream>>>(hbf2, meta, csr, mbuf);
  // layer 2: h3 -> h1 (f32 only; consumed by k_pq2)
  k_gemm   <<<(N_NODES + 63) / 64, 256, 0, stream>>>(h2, mbuf, w2, root2, b2, h1, (uint16_t*)nullptr);

  k_pq2    <<<(N_NODES + 63) / 64, 256, 0, stream>>>(h1, dw1, db1, Pb, Qb);
  k_dec    <<<N_EDGES / 256, 256, 0, stream>>>(ei, ea, Pb, Qb, dw1, dw2, db2, dw3, db3, out);
}

// Round 8
// 374.835 us; speedup vs baseline: 4.4665x; 1.1536x over previous
//
#include <hip/hip_runtime.h>
#include <stdint.h>

#define N_NODES 50000
#define N_EDGES 1600000
#define NBLK_N 196        // ceil(50000/256)
#define NB 391            // buckets of 128 dst nodes
#define BPAD 8192         // padded bucket capacity
#define CHUNK 4096        // edges per prep workgroup
#define NWG_PREP 391      // ceil(1.6M/4096)

__device__ inline float bf2f(uint16_t u) {
  union { uint32_t i; float f; } c; c.i = (uint32_t)u << 16; return c.f;
}
__device__ inline uint16_t f2bf(float f) {
  union { uint32_t i; float f; } c; c.f = f;
  uint32_t b = c.i;
  b += 0x7FFFu + ((b >> 16) & 1u);   // round to nearest even
  return (uint16_t)(b >> 16);
}
__device__ inline float bflo(uint32_t w) {
  union { uint32_t i; float f; } c; c.i = w << 16; return c.f;
}
__device__ inline float bfhi(uint32_t w) {
  union { uint32_t i; float f; } c; c.i = w & 0xFFFF0000u; return c.f;
}

// ---------------------------------------------------------------------------
// Prep + pass-1 binning (NO global cnt3 atomics — counts derived later)
// ---------------------------------------------------------------------------
__global__ __launch_bounds__(256) void k_prep(const int* __restrict__ ei,
                                              const float* __restrict__ ea,
                                              int* __restrict__ bcur,
                                              uint32_t* __restrict__ pairbuf) {
  __shared__ int hist[NB];
  __shared__ int hbase[NB];
  int t = threadIdx.x;
  int base = blockIdx.x * CHUNK;
  for (int i = t; i < NB; i += 256) hist[i] = 0;
  __syncthreads();

  uint32_t wreg[16];
  int breg[16];
  #pragma unroll
  for (int k = 0; k < 16; k++) {
    int e = base + t + k * 256;
    breg[k] = -1;
    if (e < N_EDGES) {
      float dist = ea[(size_t)e * 6];
      int rel = (dist > 5000.0f) + (dist > 10000.0f);
      int s = ei[e];
      int d = ei[N_EDGES + e];
      wreg[k] = (uint32_t)s | ((uint32_t)rel << 16) | ((uint32_t)(d & 127) << 24);
      breg[k] = d >> 7;
      atomicAdd(&hist[breg[k]], 1);
    }
  }
  __syncthreads();
  for (int i = t; i < NB; i += 256) {
    int h = hist[i];
    hbase[i] = h ? atomicAdd(&bcur[i], h) : 0;
    hist[i] = 0;
  }
  __syncthreads();
  #pragma unroll
  for (int k = 0; k < 16; k++) {
    int b = breg[k];
    if (b >= 0) {
      int r = atomicAdd(&hist[b], 1);
      pairbuf[(size_t)b * BPAD + hbase[b] + r] = wreg[k];
    }
  }
}

// ---------------------------------------------------------------------------
// Per-bucket (node,rel) counting from binned pairbuf -> cnt3 (coalesced write)
// ---------------------------------------------------------------------------
__global__ __launch_bounds__(256) void k_count(const uint32_t* __restrict__ pairbuf,
                                               const int* __restrict__ bcur,
                                               int* __restrict__ cnt3) {
  __shared__ int lc[384];   // 128 nodes x 3 rels
  int b = blockIdx.x;
  int t = threadIdx.x;
  for (int i = t; i < 384; i += 256) lc[i] = 0;
  int cnt = bcur[b];
  __syncthreads();
  const uint32_t* pb = pairbuf + (size_t)b * BPAD;
  for (int i = t; i < cnt; i += 256) {
    uint32_t w = pb[i];
    int dl  = (int)(w >> 24);
    int rel = (int)((w >> 16) & 3u);
    atomicAdd(&lc[dl * 3 + rel], 1);
  }
  __syncthreads();
  int gbase = b * 384;   // == (b*128)*3
  for (int j = t; j < 384; j += 256) {
    int node = (b << 7) + (j / 3);
    if (node < N_NODES) cnt3[gbase + j] = lc[j];
  }
}

// ---------------------------------------------------------------------------
// Parallel scan of node degrees
// ---------------------------------------------------------------------------
__global__ __launch_bounds__(256) void k_scanA(const int* __restrict__ cnt3,
                                               int* __restrict__ excl,
                                               int* __restrict__ bsum) {
  __shared__ int s[256];
  int t = threadIdx.x;
  int n = blockIdx.x * 256 + t;
  int deg = 0;
  if (n < N_NODES) deg = cnt3[3 * n] + cnt3[3 * n + 1] + cnt3[3 * n + 2];
  s[t] = deg;
  __syncthreads();
  for (int ofs = 1; ofs < 256; ofs <<= 1) {
    int v = (t >= ofs) ? s[t - ofs] : 0;
    __syncthreads();
    s[t] += v;
    __syncthreads();
  }
  if (n < N_NODES) excl[n] = s[t] - deg;
  if (t == 255) bsum[blockIdx.x] = s[255];
}

__global__ __launch_bounds__(256) void k_scanB(int* __restrict__ bsum) {
  __shared__ int s[256];
  int t = threadIdx.x;
  int v = (t < NBLK_N) ? bsum[t] : 0;
  s[t] = v;
  __syncthreads();
  for (int ofs = 1; ofs < 256; ofs <<= 1) {
    int u = (t >= ofs) ? s[t - ofs] : 0;
    __syncthreads();
    s[t] += u;
    __syncthreads();
  }
  if (t < NBLK_N) bsum[t] = s[t] - v;   // exclusive
}

__global__ __launch_bounds__(256) void k_scanC(const int* __restrict__ cnt3,
                                               const int* __restrict__ excl,
                                               const int* __restrict__ bsum,
                                               int4* __restrict__ meta,
                                               const float* __restrict__ x,
                                               float4* __restrict__ x4) {
  int n = blockIdx.x * 256 + threadIdx.x;
  if (n >= N_NODES) return;
  meta[n] = make_int4(bsum[blockIdx.x] + excl[n],
                      cnt3[3 * n], cnt3[3 * n + 1], cnt3[3 * n + 2]);
  x4[n] = make_float4(x[n * 3], x[n * 3 + 1], x[n * 3 + 2], 0.0f);
}

// ---------------------------------------------------------------------------
// Pass-2 scatter
// ---------------------------------------------------------------------------
__global__ __launch_bounds__(256) void k_scat2(const uint32_t* __restrict__ pairbuf,
                                               const int* __restrict__ bcur,
                                               const int4* __restrict__ meta,
                                               uint32_t* __restrict__ csr) {
  __shared__ int lcur[128];
  int b = blockIdx.x;
  int t = threadIdx.x;
  int node0 = b << 7;
  if (t < 128) {
    int n = node0 + t;
    lcur[t] = (n < N_NODES) ? meta[n].x : 0;
  }
  int cnt = bcur[b];
  __syncthreads();
  const uint32_t* pb = pairbuf + (size_t)b * BPAD;
  for (int i = t; i < cnt; i += 256) {
    uint32_t w = pb[i];
    int dl = (int)(w >> 24);
    int p = atomicAdd(&lcur[dl], 1);
    csr[p] = w & 0x00FFFFFFu;   // src | rel<<16
  }
}

// ---------------------------------------------------------------------------
// Layer 0: din=3. Wave per node; writes f32 h + bf16 shadow.
// ---------------------------------------------------------------------------
__global__ __launch_bounds__(256) void k_layer0(const float4* __restrict__ x4,
                                                const float* __restrict__ W0,
                                                const float* __restrict__ root0,
                                                const float* __restrict__ b0,
                                                const int4* __restrict__ meta,
                                                const uint32_t* __restrict__ csr,
                                                float* __restrict__ hout,
                                                uint16_t* __restrict__ hbf) {
  __shared__ float sW[576], sR[192], sb[64];
  int t = threadIdx.x;
  for (int i = t; i < 576; i += 256) sW[i] = W0[i];
  for (int i = t; i < 192; i += 256) sR[i] = root0[i];
  if (t < 64) sb[t] = b0[t];
  __syncthreads();
  int wid = t >> 6, lane = t & 63;
  int n = blockIdx.x * 4 + wid;
  int4 md = meta[n];
  int off = md.x, c0 = md.y, c1 = md.z, c2 = md.w;
  int cnt = c0 + c1 + c2;
  float a00 = 0, a01 = 0, a02 = 0, a10 = 0, a11 = 0, a12 = 0, a20 = 0, a21 = 0, a22 = 0;
  for (int base = 0; base < cnt; base += 64) {
    int idx = base + lane;
    float4 v = make_float4(0, 0, 0, 0);
    int r = 3;
    if (idx < cnt) {
      uint32_t u = csr[off + idx];
      r = (int)(u >> 16);
      v = x4[u & 0xFFFFu];
    }
    a00 += (r == 0) ? v.x : 0.0f; a01 += (r == 0) ? v.y : 0.0f; a02 += (r == 0) ? v.z : 0.0f;
    a10 += (r == 1) ? v.x : 0.0f; a11 += (r == 1) ? v.y : 0.0f; a12 += (r == 1) ? v.z : 0.0f;
    a20 += (r == 2) ? v.x : 0.0f; a21 += (r == 2) ? v.y : 0.0f; a22 += (r == 2) ? v.z : 0.0f;
  }
  #pragma unroll
  for (int d = 1; d < 64; d <<= 1) {
    a00 += __shfl_xor(a00, d); a01 += __shfl_xor(a01, d); a02 += __shfl_xor(a02, d);
    a10 += __shfl_xor(a10, d); a11 += __shfl_xor(a11, d); a12 += __shfl_xor(a12, d);
    a20 += __shfl_xor(a20, d); a21 += __shfl_xor(a21, d); a22 += __shfl_xor(a22, d);
  }
  float i0 = 1.0f / (float)(c0 > 1 ? c0 : 1);
  float i1 = 1.0f / (float)(c1 > 1 ? c1 : 1);
  float i2 = 1.0f / (float)(c2 > 1 ? c2 : 1);
  float4 xn = x4[n];
  float in[12];
  in[0] = xn.x; in[1] = xn.y; in[2] = xn.z;
  in[3] = a00 * i0; in[4] = a01 * i0; in[5] = a02 * i0;
  in[6] = a10 * i1; in[7] = a11 * i1; in[8] = a12 * i1;
  in[9] = a20 * i2; in[10] = a21 * i2; in[11] = a22 * i2;
  float acc = sb[lane];
  #pragma unroll
  for (int k = 0; k < 3; k++) acc = fmaf(in[k], sR[k * 64 + lane], acc);
  #pragma unroll
  for (int k = 0; k < 9; k++) acc = fmaf(in[3 + k], sW[k * 64 + lane], acc);
  float h = fmaxf(acc, 0.0f);
  hout[(size_t)n * 64 + lane] = h;
  hbf[(size_t)n * 64 + lane] = f2bf(h);
}

// ---------------------------------------------------------------------------
// Aggregation: wave per node, lane = feature, bf16 gathers (128 B/edge).
// ---------------------------------------------------------------------------
#define ACC(E, V) { int r_ = (int)((E) >> 16); \
  a0 += (r_ == 0) ? (V) : 0.0f; a1 += (r_ == 1) ? (V) : 0.0f; a2 += (r_ == 2) ? (V) : 0.0f; }

__global__ __launch_bounds__(256) void k_agg(const uint16_t* __restrict__ hbf,
                                             const int4* __restrict__ meta,
                                             const uint32_t* __restrict__ csr,
                                             float* __restrict__ mbuf) {
  int t = threadIdx.x, wid = t >> 6, lane = t & 63;
  int n = blockIdx.x * 4 + wid;
  int4 md = meta[n];
  int off = __builtin_amdgcn_readfirstlane(md.x);
  int c0  = __builtin_amdgcn_readfirstlane(md.y);
  int c1  = __builtin_amdgcn_readfirstlane(md.z);
  int c2  = __builtin_amdgcn_readfirstlane(md.w);
  int cnt = c0 + c1 + c2;
  const uint32_t* cp = csr + off;
  float a0 = 0, a1 = 0, a2 = 0;
  int i = 0;
  for (; i + 8 <= cnt; i += 8) {
    uint32_t e0 = cp[i],     e1 = cp[i + 1], e2 = cp[i + 2], e3 = cp[i + 3];
    uint32_t e4 = cp[i + 4], e5 = cp[i + 5], e6 = cp[i + 6], e7 = cp[i + 7];
    float v0 = bf2f(hbf[(int)((e0 & 0xFFFFu) << 6) + lane]);
    float v1 = bf2f(hbf[(int)((e1 & 0xFFFFu) << 6) + lane]);
    float v2 = bf2f(hbf[(int)((e2 & 0xFFFFu) << 6) + lane]);
    float v3 = bf2f(hbf[(int)((e3 & 0xFFFFu) << 6) + lane]);
    float v4 = bf2f(hbf[(int)((e4 & 0xFFFFu) << 6) + lane]);
    float v5 = bf2f(hbf[(int)((e5 & 0xFFFFu) << 6) + lane]);
    float v6 = bf2f(hbf[(int)((e6 & 0xFFFFu) << 6) + lane]);
    float v7 = bf2f(hbf[(int)((e7 & 0xFFFFu) << 6) + lane]);
    ACC(e0, v0) ACC(e1, v1) ACC(e2, v2) ACC(e3, v3)
    ACC(e4, v4) ACC(e5, v5) ACC(e6, v6) ACC(e7, v7)
  }
  for (; i < cnt; i++) {
    uint32_t e = cp[i];
    float v = bf2f(hbf[(int)((e & 0xFFFFu) << 6) + lane]);
    ACC(e, v)
  }
  float* mb = mbuf + (size_t)n * 192;
  mb[lane]       = a0 * (1.0f / (float)(c0 > 1 ? c0 : 1));
  mb[64 + lane]  = a1 * (1.0f / (float)(c1 > 1 ? c1 : 1));
  mb[128 + lane] = a2 * (1.0f / (float)(c2 > 1 ? c2 : 1));
}

// ---------------------------------------------------------------------------
// Transform GEMM: f32; epilogue writes f32 h (+ optional bf16 shadow)
// ---------------------------------------------------------------------------
__global__ __launch_bounds__(256) void k_gemm(const float* __restrict__ hin,
                                              const float* __restrict__ mbuf,
                                              const float* __restrict__ W,
                                              const float* __restrict__ root,
                                              const float* __restrict__ b,
                                              float* __restrict__ hout,
                                              uint16_t* __restrict__ hbf) {
  __shared__ float As[64 * 84];
  __shared__ float Bs[64 * 64];
  __shared__ float sb[64];
  int t = threadIdx.x;
  int bn = blockIdx.x * 64;
  if (t < 64) sb[t] = b[t];
  int tn = t & 15, to = t >> 4;
  float acc[4][4] = {};
  for (int kb = 0; kb < 4; kb++) {
    const float4* Bsrc = (const float4*)((kb == 0) ? root : (W + (size_t)(kb - 1) * 4096));
    for (int i2 = t; i2 < 1024; i2 += 256) ((float4*)Bs)[i2] = Bsrc[i2];
    int r = t >> 2;
    int node = bn + r;
    bool ok = node < N_NODES;
    const float* Arow = (kb == 0) ? (hin + (size_t)node * 64)
                                  : (mbuf + (size_t)node * 192 + (size_t)(kb - 1) * 64);
    #pragma unroll
    for (int ii = 0; ii < 4; ii++) {
      int c4 = (t & 3) + 4 * ii;
      float4 v = ok ? ((const float4*)Arow)[c4] : make_float4(0, 0, 0, 0);
      *(float4*)&As[r * 84 + c4 * 4] = v;
    }
    __syncthreads();
    #pragma unroll
    for (int k4 = 0; k4 < 16; k4++) {
      float4 a0 = *(const float4*)&As[(tn)      * 84 + k4 * 4];
      float4 a1 = *(const float4*)&As[(tn + 16) * 84 + k4 * 4];
      float4 a2 = *(const float4*)&As[(tn + 32) * 84 + k4 * 4];
      float4 a3 = *(const float4*)&As[(tn + 48) * 84 + k4 * 4];
      float4 b0 = *(const float4*)&Bs[(k4 * 4 + 0) * 64 + to * 4];
      float4 b1 = *(const float4*)&Bs[(k4 * 4 + 1) * 64 + to * 4];
      float4 b2 = *(const float4*)&Bs[(k4 * 4 + 2) * 64 + to * 4];
      float4 b3 = *(const float4*)&Bs[(k4 * 4 + 3) * 64 + to * 4];
      const float* av[4] = {&a0.x, &a1.x, &a2.x, &a3.x};
      const float* bv[4] = {&b0.x, &b1.x, &b2.x, &b3.x};
      #pragma unroll
      for (int c = 0; c < 4; c++)
        #pragma unroll
        for (int i3 = 0; i3 < 4; i3++)
          #pragma unroll
          for (int j = 0; j < 4; j++)
            acc[i3][j] = fmaf(av[i3][c], bv[c][j], acc[i3][j]);
    }
    __syncthreads();
  }
  #pragma unroll
  for (int i3 = 0; i3 < 4; i3++) {
    int node = bn + tn + 16 * i3;
    if (node < N_NODES) {
      float4 o;
      o.x = fmaxf(acc[i3][0] + sb[to * 4 + 0], 0.0f);
      o.y = fmaxf(acc[i3][1] + sb[to * 4 + 1], 0.0f);
      o.z = fmaxf(acc[i3][2] + sb[to * 4 + 2], 0.0f);
      o.w = fmaxf(acc[i3][3] + sb[to * 4 + 3], 0.0f);
      *(float4*)(hout + (size_t)node * 64 + to * 4) = o;
      if (hbf) {
        uint2 pk;
        pk.x = (uint32_t)f2bf(o.x) | ((uint32_t)f2bf(o.y) << 16);
        pk.y = (uint32_t)f2bf(o.z) | ((uint32_t)f2bf(o.w) << 16);
        *(uint2*)(hbf + (size_t)node * 64 + to * 4) = pk;
      }
    }
  }
}

// ---------------------------------------------------------------------------
// P/Q projection GEMM: [64-node tile] x [dw1_A | dw1_B] (64x64), K=64.
// ---------------------------------------------------------------------------
__global__ __launch_bounds__(256) void k_pq2(const float* __restrict__ h,
                                             const float* __restrict__ dw1,
                                             const float* __restrict__ db1,
                                             uint16_t* __restrict__ Pb,
                                             uint16_t* __restrict__ Qb) {
  __shared__ float As[64 * 84];
  __shared__ float Bs[64 * 64];
  __shared__ float sdb1[32];
  int t = threadIdx.x;
  int bn = blockIdx.x * 64;
  if (t < 32) sdb1[t] = db1[t];
  {
    int r = t >> 2;
    int node = bn + r;
    bool ok = node < N_NODES;
    const float* Arow = h + (size_t)node * 64;
    #pragma unroll
    for (int ii = 0; ii < 4; ii++) {
      int c4 = (t & 3) + 4 * ii;
      float4 v = ok ? ((const float4*)Arow)[c4] : make_float4(0, 0, 0, 0);
      *(float4*)&As[r * 84 + c4 * 4] = v;
    }
  }
  for (int i = t; i < 4096; i += 256) {
    int k = i >> 6, j = i & 63;
    Bs[i] = (j < 32) ? dw1[k * 32 + j] : dw1[(64 + k) * 32 + (j - 32)];
  }
  __syncthreads();
  int tn = t & 15, to = t >> 4;
  float acc[4][4] = {};
  #pragma unroll
  for (int k4 = 0; k4 < 16; k4++) {
    float4 a0 = *(const float4*)&As[(tn)      * 84 + k4 * 4];
    float4 a1 = *(const float4*)&As[(tn + 16) * 84 + k4 * 4];
    float4 a2 = *(const float4*)&As[(tn + 32) * 84 + k4 * 4];
    float4 a3 = *(const float4*)&As[(tn + 48) * 84 + k4 * 4];
    float4 b0 = *(const float4*)&Bs[(k4 * 4 + 0) * 64 + to * 4];
    float4 b1 = *(const float4*)&Bs[(k4 * 4 + 1) * 64 + to * 4];
    float4 b2 = *(const float4*)&Bs[(k4 * 4 + 2) * 64 + to * 4];
    float4 b3 = *(const float4*)&Bs[(k4 * 4 + 3) * 64 + to * 4];
    const float* av[4] = {&a0.x, &a1.x, &a2.x, &a3.x};
    const float* bv[4] = {&b0.x, &b1.x, &b2.x, &b3.x};
    #pragma unroll
    for (int c = 0; c < 4; c++)
      #pragma unroll
      for (int i3 = 0; i3 < 4; i3++)
        #pragma unroll
        for (int j = 0; j < 4; j++)
          acc[i3][j] = fmaf(av[i3][c], bv[c][j], acc[i3][j]);
  }
  bool isP = (to < 8);
  float bias0 = isP ? sdb1[to * 4 + 0] : 0.0f;
  float bias1 = isP ? sdb1[to * 4 + 1] : 0.0f;
  float bias2 = isP ? sdb1[to * 4 + 2] : 0.0f;
  float bias3 = isP ? sdb1[to * 4 + 3] : 0.0f;
  #pragma unroll
  for (int i3 = 0; i3 < 4; i3++) {
    int node = bn + tn + 16 * i3;
    if (node < N_NODES) {
      float v0 = acc[i3][0] + bias0;
      float v1 = acc[i3][1] + bias1;
      float v2 = acc[i3][2] + bias2;
      float v3 = acc[i3][3] + bias3;
      uint2 pk;
      pk.x = (uint32_t)f2bf(v0) | ((uint32_t)f2bf(v1) << 16);
      pk.y = (uint32_t)f2bf(v2) | ((uint32_t)f2bf(v3) << 16);
      if (isP) *(uint2*)(Pb + (size_t)node * 32 + to * 4) = pk;
      else     *(uint2*)(Qb + (size_t)node * 32 + (to - 8) * 4) = pk;
    }
  }
}

// ---------------------------------------------------------------------------
// Decoder edge pass: bf16 P/Q gathers (one 64 B line per row)
// ---------------------------------------------------------------------------
__global__ __launch_bounds__(256) void k_dec(const int* __restrict__ ei,
                                             const float* __restrict__ ea,
                                             const uint16_t* __restrict__ Pb,
                                             const uint16_t* __restrict__ Qb,
                                             const float* __restrict__ dw1,
                                             const float* __restrict__ dw2,
                                             const float* __restrict__ db2,
                                             const float* __restrict__ dw3,
                                             const float* __restrict__ db3,
                                             float* __restrict__ out) {
  __shared__ float C[6 * 32], W2[32 * 16], sb2[16], W3[16];
  __shared__ float sb3;
  int t = threadIdx.x;
  for (int i = t; i < 192; i += 256) C[i] = dw1[128 * 32 + i];
  for (int i = t; i < 512; i += 256) W2[i] = dw2[i];
  if (t < 16) { sb2[t] = db2[t]; W3[t] = dw3[t]; }
  if (t == 0) sb3 = db3[0];
  __syncthreads();
  int e = blockIdx.x * 256 + t;
  int s = ei[e];
  int d = ei[N_EDGES + e];
  float ea6[6];
  #pragma unroll
  for (int i = 0; i < 6; i++) ea6[i] = ea[(size_t)e * 6 + i];
  const uint4* Ps = (const uint4*)(Pb + (size_t)s * 32);
  const uint4* Qd = (const uint4*)(Qb + (size_t)d * 32);
  float z1[32];
  #pragma unroll
  for (int j4 = 0; j4 < 4; j4++) {
    uint4 pv = Ps[j4];
    uint4 qv = Qd[j4];
    const uint32_t* pw = &pv.x;
    const uint32_t* qw = &qv.x;
    #pragma unroll
    for (int c = 0; c < 4; c++) {
      int j = j4 * 8 + c * 2;
      float vlo = bflo(pw[c]) + bflo(qw[c]);
      float vhi = bfhi(pw[c]) + bfhi(qw[c]);
      #pragma unroll
      for (int k = 0; k < 6; k++) {
        vlo = fmaf(ea6[k], C[k * 32 + j], vlo);
        vhi = fmaf(ea6[k], C[k * 32 + j + 1], vhi);
      }
      z1[j]     = fmaxf(vlo, 0.0f);
      z1[j + 1] = fmaxf(vhi, 0.0f);
    }
  }
  float o = sb3;
  #pragma unroll
  for (int i = 0; i < 16; i++) {
    float z = sb2[i];
    #pragma unroll
    for (int j = 0; j < 32; j++) z = fmaf(z1[j], W2[j * 16 + i], z);
    o = fmaf(fmaxf(z, 0.0f), W3[i], o);
  }
  out[e] = o;
}

// ---------------------------------------------------------------------------
extern "C" void kernel_launch(void* const* d_in, const int* in_sizes, int n_in,
                              void* d_out, int out_size, void* d_ws, size_t ws_size,
                              hipStream_t stream) {
  const float* x      = (const float*)d_in[0];
  const int*   ei     = (const int*)d_in[1];
  const float* ea     = (const float*)d_in[2];
  const float* w0     = (const float*)d_in[3];
  const float* root0  = (const float*)d_in[4];
  const float* b0     = (const float*)d_in[5];
  const float* w1     = (const float*)d_in[6];
  const float* root1  = (const float*)d_in[7];
  const float* b1     = (const float*)d_in[8];
  const float* w2     = (const float*)d_in[9];
  const float* root2  = (const float*)d_in[10];
  const float* b2     = (const float*)d_in[11];
  const float* dw1    = (const float*)d_in[12];
  const float* db1    = (const float*)d_in[13];
  const float* dw2    = (const float*)d_in[14];
  const float* db2    = (const float*)d_in[15];
  const float* dw3    = (const float*)d_in[16];
  const float* db3    = (const float*)d_in[17];
  float* out = (float*)d_out;

  char* w = (char*)d_ws;
  int* cnt3        = (int*)w;       w += (size_t)N_NODES * 3 * 4;
  int* bcur        = (int*)w;       w += (size_t)NB * 4;
  int4* meta       = (int4*)w;      w += (size_t)N_NODES * 16;
  uint32_t* csr    = (uint32_t*)w;  w += (size_t)N_EDGES * 4;
  float4* x4       = (float4*)w;    w += (size_t)N_NODES * 16;
  float* h1        = (float*)w;     w += (size_t)N_NODES * 64 * 4;
  float* h2        = (float*)w;     w += (size_t)N_NODES * 64 * 4;
  float* mbuf      = (float*)w;     w += (size_t)N_NODES * 192 * 4;
  uint16_t* hbf1   = (uint16_t*)w;  w += (size_t)N_NODES * 64 * 2;
  uint16_t* hbf2   = (uint16_t*)w;  w += (size_t)N_NODES * 64 * 2;
  uint16_t* Pb     = hbf1;
  uint16_t* Qb     = hbf2;
  uint32_t* pairbuf = (uint32_t*)h1;            // 12.81 MB, aliases h1+h2 head
  int* excl        = (int*)mbuf;
  int* bsum        = (int*)mbuf + N_NODES;

  hipMemsetAsync(bcur, 0, (size_t)NB * 4, stream);

  k_prep   <<<NWG_PREP, 256, 0, stream>>>(ei, ea, bcur, pairbuf);
  k_count  <<<NB, 256, 0, stream>>>(pairbuf, bcur, cnt3);
  k_scanA  <<<NBLK_N, 256, 0, stream>>>(cnt3, excl, bsum);
  k_scanB  <<<1, 256, 0, stream>>>(bsum);
  k_scanC  <<<NBLK_N, 256, 0, stream>>>(cnt3, excl, bsum, meta, x, x4);
  k_scat2  <<<NB, 256, 0, stream>>>(pairbuf, bcur, meta, csr);

  k_layer0 <<<N_NODES / 4, 256, 0, stream>>>(x4, w0, root0, b0, meta, csr, h1, hbf1);

  k_agg    <<<N_NODES / 4, 256, 0, stream>>>(hbf1, meta, csr, mbuf);
  k_gemm   <<<(N_NODES + 63) / 64, 256, 0, stream>>>(h1, mbuf, w1, root1, b1, h2, hbf2);

  k_agg    <<<N_NODES / 4, 256, 0, stream>>>(hbf2, meta, csr, mbuf);
  k_gemm   <<<(N_NODES + 63) / 64, 256, 0, stream>>>(h2, mbuf, w2, root2, b2, h1, (uint16_t*)nullptr);

  k_pq2    <<<(N_NODES + 63) / 64, 256, 0, stream>>>(h1, dw1, db1, Pb, Qb);
  k_dec    <<<N_EDGES / 256, 256, 0, stream>>>(ei, ea, Pb, Qb, dw1, dw2, db2, dw3, db3, out);
}